// Round 10
// baseline (215.674 us; speedup 1.0000x reference)
//
#include <hip/hip_runtime.h>
#include <hip/hip_bf16.h>
#include <cstdint>

typedef __attribute__((ext_vector_type(8))) short short8;
typedef __attribute__((ext_vector_type(4))) float f32x4;
typedef __attribute__((ext_vector_type(2))) unsigned int uint2v;
typedef unsigned short ushort_t;

#define S_LEN 2048
#define D_DIM 1024
#define NH 16
#define DK 64
#define BATCH 2
#define M_ROWS (BATCH * S_LEN)   // 4096
#define BK 32

__device__ inline ushort_t f2bf(float f) {
    union { float f; uint32_t u; } v; v.f = f;
    uint32_t r = v.u + 0x7fffu + ((v.u >> 16) & 1u);  // RNE
    return (ushort_t)(r >> 16);
}

__device__ __forceinline__ ushort_t bfc(float f) {
    __hip_bfloat16 h = __float2bfloat16(f);          // HW cvt path
    return __builtin_bit_cast(ushort_t, h);
}

__device__ __forceinline__ float bf2f(ushort_t u) {
    return __uint_as_float(((uint32_t)u) << 16);
}

// HW transcendentals (OCML exp2f/div are multi-instruction without fast-math)
__device__ __forceinline__ float fexp2(float x) {
#if __has_builtin(__builtin_amdgcn_exp2f)
    return __builtin_amdgcn_exp2f(x);
#else
    return exp2f(x);
#endif
}
__device__ __forceinline__ float frcp(float x) {
#if __has_builtin(__builtin_amdgcn_rcpf)
    return __builtin_amdgcn_rcpf(x);
#else
    return 1.0f / x;
#endif
}

__device__ __forceinline__ void glds16(const ushort_t* g, ushort_t* l) {
    __builtin_amdgcn_global_load_lds(
        (const __attribute__((address_space(1))) uint32_t*)g,
        (__attribute__((address_space(3))) uint32_t*)l,
        16, 0, 0);
}

#if __has_builtin(__builtin_amdgcn_permlane16_swap) && __has_builtin(__builtin_amdgcn_permlane32_swap)
#define HAS_PLSWAP 1
#else
#define HAS_PLSWAP 0
#endif

// cross-lane reduce over the 4 16-lane groups (lanes l, l^16, l^32, l^48)
__device__ __forceinline__ float red_max4(float x) {
#if HAS_PLSWAP
    uint2v a = __builtin_amdgcn_permlane16_swap(__float_as_uint(x), __float_as_uint(x), false, false);
    float y = fmaxf(__uint_as_float(a.x), __uint_as_float(a.y));
    uint2v b = __builtin_amdgcn_permlane32_swap(__float_as_uint(y), __float_as_uint(y), false, false);
    return fmaxf(__uint_as_float(b.x), __uint_as_float(b.y));
#else
    x = fmaxf(x, __shfl_xor(x, 16));
    return fmaxf(x, __shfl_xor(x, 32));
#endif
}
__device__ __forceinline__ float red_sum4(float x) {
#if HAS_PLSWAP
    uint2v a = __builtin_amdgcn_permlane16_swap(__float_as_uint(x), __float_as_uint(x), false, false);
    float y = __uint_as_float(a.x) + __uint_as_float(a.y);
    uint2v b = __builtin_amdgcn_permlane32_swap(__float_as_uint(y), __float_as_uint(y), false, false);
    return __uint_as_float(b.x) + __uint_as_float(b.y);
#else
    x += __shfl_xor(x, 16);
    return x + __shfl_xor(x, 32);
#endif
}

// T12 route: build PV A-frag words F[0..3] for k-slice ks from packed P words
// wp[n][h] (kv = 16n + 4*(lane>>4) + 2h + {0,1}, q = lane&15).
__device__ __forceinline__ void route_p(const uint32_t wp[4][2], int ks, int lane, uint32_t F[4]) {
#if HAS_PLSWAP
    uint32_t U0 = wp[2 * ks][0],     U1 = wp[2 * ks][1];
    uint32_t V0 = wp[2 * ks + 1][0], V1 = wp[2 * ks + 1][1];
    uint2v t, pa0, pa1, pb0, pb1;
    t = __builtin_amdgcn_permlane32_swap(U0, U0, false, false);
    pa0 = __builtin_amdgcn_permlane16_swap(U0, t.y, false, false);
    t = __builtin_amdgcn_permlane32_swap(U1, U1, false, false);
    pa1 = __builtin_amdgcn_permlane16_swap(U1, t.y, false, false);
    t = __builtin_amdgcn_permlane32_swap(V0, V0, false, false);
    pb0 = __builtin_amdgcn_permlane16_swap(t.x, V0, false, false);
    t = __builtin_amdgcn_permlane32_swap(V1, V1, false, false);
    pb1 = __builtin_amdgcn_permlane16_swap(t.x, V1, false, false);
    bool lo = lane < 32;
    F[0] = lo ? pa0.x : pb0.x;
    F[1] = lo ? pa1.x : pb1.x;
    F[2] = lo ? pa0.y : pb0.y;
    F[3] = lo ? pa1.y : pb1.y;
#else
    int q = lane & 15, g = lane >> 4;
#pragma unroll
    for (int m = 0; m < 4; m++) {
        int src = 16 * (2 * (g & 1) + (m >> 1)) + q;
        uint32_t xa = (uint32_t)__shfl((int)wp[2 * ks][m & 1], src);
        uint32_t xb = (uint32_t)__shfl((int)wp[2 * ks + 1][m & 1], src);
        F[m] = (g < 2) ? xa : xb;
    }
#endif
}

// ---------------- fp32 -> bf16 convert (vectorized) ----------------
__global__ void cvt_bf16(const float* __restrict__ in, ushort_t* __restrict__ out, int n4) {
    int i = blockIdx.x * blockDim.x + threadIdx.x;
    int stride = gridDim.x * blockDim.x;
    for (int idx = i; idx < n4; idx += stride) {
        float4 v = ((const float4*)in)[idx];
        ushort4 o;
        o.x = f2bf(v.x); o.y = f2bf(v.y); o.z = f2bf(v.z); o.w = f2bf(v.w);
        ((ushort4*)out)[idx] = o;
    }
}

// fused convert of Wq,Wk,Wv into one [3072,1024] bf16 buffer
__global__ void cvt_w3(const float* __restrict__ wq, const float* __restrict__ wk,
                       const float* __restrict__ wv, ushort_t* __restrict__ wqkv) {
    const int seg = (D_DIM * D_DIM) / 4;   // 2^18
    int i = blockIdx.x * blockDim.x + threadIdx.x;
    int stride = gridDim.x * blockDim.x;
    for (int idx = i; idx < 3 * seg; idx += stride) {
        int sel = idx >> 18;
        int id = idx & (seg - 1);
        const float* src = sel == 0 ? wq : (sel == 1 ? wk : wv);
        float4 v = ((const float4*)src)[id];
        ushort4 o;
        o.x = f2bf(v.x); o.y = f2bf(v.y); o.z = f2bf(v.z); o.w = f2bf(v.w);
        ((ushort4*)wqkv)[sel * seg + id] = o;
    }
}

// ---------------- GEMM: C = A[M,K] * Bw[N,K]^T + bias ----------------
// T1: bijective XCD remap (grid must be a multiple of 8 blocks).
template<int MODE, int BMt, int BNt>
__global__ __launch_bounds__(256) void gemm_bt(const ushort_t* __restrict__ A,
                                               const ushort_t* __restrict__ Bw,
                                               const float* __restrict__ b0,
                                               const float* __restrict__ b1,
                                               const float* __restrict__ b2,
                                               void* __restrict__ C0,
                                               void* __restrict__ C1,
                                               void* __restrict__ C2,
                                               int M, int N, int K) {
    constexpr int FM = BMt / 32, FN = BNt / 32;
    constexpr int ACH = BMt / 64, BCH = BNt / 64;
    __shared__ ushort_t As[BMt * BK];
    __shared__ ushort_t Bs[BNt * BK];
    int tid = threadIdx.x;
    int lane = tid & 63;
    int w = tid >> 6;
    int wr = w >> 1, wc = w & 1;
    // XCD-aware remap: consecutive logical tiles (same A panel) -> same XCD L2
    int nwg = gridDim.x;
    int bx = (blockIdx.x & 7) * (nwg >> 3) + (blockIdx.x >> 3);
    int ntile = N / BNt;
    int m0 = (bx / ntile) * BMt;
    int n0 = (bx % ntile) * BNt;
    int lr = lane & 15;
    int lk = (lane >> 4) * 8;
    int srow = lane >> 2;            // 0..15
    int scol = (lane & 3) * 8;

    f32x4 acc[FM][FN] = {};

    for (int kt = 0; kt < K; kt += BK) {
        __syncthreads();
#pragma unroll
        for (int c = 0; c < ACH; c++)
            glds16(&A[(size_t)(m0 + w * (BMt / 4) + c * 16 + srow) * K + kt + scol],
                   &As[(w * (BMt / 4) + c * 16) * BK]);
#pragma unroll
        for (int c = 0; c < BCH; c++)
            glds16(&Bw[(size_t)(n0 + w * (BNt / 4) + c * 16 + srow) * K + kt + scol],
                   &Bs[(w * (BNt / 4) + c * 16) * BK]);
        __syncthreads();

        short8 af[FM], bf[FN];
#pragma unroll
        for (int f = 0; f < FM; f++)
            af[f] = *(const short8*)&As[(wr * (BMt / 2) + f * 16 + lr) * BK + lk];
#pragma unroll
        for (int f = 0; f < FN; f++)
            bf[f] = *(const short8*)&Bs[(wc * (BNt / 2) + f * 16 + lr) * BK + lk];
#pragma unroll
        for (int i = 0; i < FM; i++)
#pragma unroll
            for (int j = 0; j < FN; j++)
                acc[i][j] = __builtin_amdgcn_mfma_f32_16x16x32_bf16(af[i], bf[j], acc[i][j], 0, 0, 0);
    }

    int r0 = (lane >> 4) * 4;
#pragma unroll
    for (int j = 0; j < FN; j++) {
        int ncol = n0 + wc * (BNt / 2) + j * 16 + lr;
        if (MODE == 2) {
            float bv = b0[ncol];
#pragma unroll
            for (int i = 0; i < FM; i++) {
                int mbase = m0 + wr * (BMt / 2) + i * 16 + r0;
#pragma unroll
                for (int r = 0; r < 4; r++)
                    ((float*)C0)[(size_t)(mbase + r) * N + ncol] = acc[i][j][r] + bv;
            }
        } else {
            int sel = n0 >> 10;                    // block-uniform
            const float* bp = sel == 0 ? b0 : (sel == 1 ? b1 : b2);
            int nc = ncol & 1023;
            float bv = bp[nc];
            int hh = nc >> 6, dk = nc & 63;
            ushort_t* Co = (ushort_t*)(sel == 0 ? C0 : (sel == 1 ? C1 : C2));
#pragma unroll
            for (int i = 0; i < FM; i++) {
                int mbase = m0 + wr * (BMt / 2) + i * 16 + r0;
                int bb = mbase >> 11, ss = mbase & 2047;
                if (sel == 2) {
                    ushort4 pk;
                    pk.x = f2bf(acc[i][j][0] + bv);
                    pk.y = f2bf(acc[i][j][1] + bv);
                    pk.z = f2bf(acc[i][j][2] + bv);
                    pk.w = f2bf(acc[i][j][3] + bv);
                    size_t idx = ((size_t)(bb * NH + hh) * DK + dk) * S_LEN + ss;
                    *(ushort4*)&Co[idx] = pk;
                } else {
#pragma unroll
                    for (int r = 0; r < 4; r++) {
                        size_t idx = ((size_t)(bb * NH + hh) * S_LEN + (ss + r)) * DK + dk;
                        Co[idx] = f2bf(acc[i][j][r] + bv);
                    }
                }
            }
        }
    }
}

// ---------------- Flash attention (causal, kv-split, LDS-free) ----------------
// Grid (bh=32, y=48), snake-balanced chunk table + stagger as round 9.
// NEW: no LDS, no barriers. K/V tiles are L2-resident (256 KB per bh);
// each wave loads its MFMA fragments directly from global (same addresses
// the LDS staging used to produce). Waves are fully independent streams ->
// latency hidden by TLP instead of intra-block pipelining.
#define CSC 0.1803368801f   // 0.125 * log2(e)

__device__ const unsigned char JTAB[48] = {
    30,31,31,15,28,29,29,30,
    25,24,13,28,27,27,26,14,
    25,26,12,22,23,23,24,11,
    19,19,18,10,22,21,21,20,
    20, 9,16,17,17,18, 8,16,
     0, 1, 2, 3, 4, 5, 6, 7};
__device__ const unsigned char KTAB[48] = {
     0, 0, 1, 9, 0, 0, 1, 1,
     0, 0, 9, 1, 1, 0, 0, 9,
     1, 1, 9, 0, 0, 1, 1, 9,
     1, 0, 0, 9, 1, 1, 0, 0,
     1, 9, 0, 0, 1, 1, 9, 1,
     9, 9, 9, 9, 9, 9, 9, 9};

__global__ __launch_bounds__(256) void attn_fwd(const ushort_t* __restrict__ Q,
                                                const ushort_t* __restrict__ K,
                                                const ushort_t* __restrict__ Vt,
                                                ushort_t* __restrict__ Oa,
                                                float2* __restrict__ ml,
                                                float* __restrict__ Pd) {
    int tid = threadIdx.x;
    int lane = tid & 63;
    int w = tid >> 6;
    int bh = blockIdx.x;           // 0..31
    int yy = blockIdx.y;           // 0..47
    int j = JTAB[yy];
    int kk = KTAB[yy];             // 0/1 = split chunk, 9 = single
    int nt = j + 1;
    int half = (nt + 1) >> 1;
    int t0 = (kk == 1) ? half : 0;
    int t1 = (kk == 0) ? half : nt;
    int cnt = t1 - t0;
    int off = yy % cnt;            // per-block stagger (same-CU mates differ)
    size_t base = (size_t)bh * S_LEN * DK;
    int q0 = j * 64;

    int lr = lane & 15;
    int lk = (lane >> 4) * 8;
    int r0 = (lane >> 4) * 4;
    int wq = w * 16 + lr;          // this lane's q row (within tile)

    // Q fragment (16 rows per wave)
    short8 qf0 = *(const short8*)&Q[base + (size_t)(q0 + wq) * DK + lk];
    short8 qf1 = *(const short8*)&Q[base + (size_t)(q0 + wq) * DK + 32 + lk];

    f32x4 o[4] = {};
    float mrowL = -1e30f, lrow = 0.f;

    for (int s = 0; s < cnt; ++s) {
        int to = s + off; if (to >= cnt) to -= cnt;
        int t = t0 + to;
        bool diag = (t == j);
        const ushort_t* Kt = K  + base + (size_t)(t * 64) * DK;
        const ushort_t* Vp = Vt + base + t * 64;

        // V fragments issued early: latency hides under QK^T + softmax
        short8 vf[4][2];
#pragma unroll
        for (int ks = 0; ks < 2; ks++) {
            if (!diag || 32 * ks <= w * 16 + 15) {
#pragma unroll
                for (int d = 0; d < 4; d++)
                    vf[d][ks] = *(const short8*)&Vp[(size_t)(d * 16 + lr) * S_LEN + ks * 32 + lk];
            }
        }

        // swapped QK^T: st rows = kv (regs), cols = q (lanes)
        f32x4 st[4] = {};
        __builtin_amdgcn_s_setprio(1);
#pragma unroll
        for (int n = 0; n < 4; n++) {
            if (!diag || n <= w) {   // skip fully-masked kv frags on diagonal
                short8 kf0 = *(const short8*)&Kt[(n * 16 + lr) * DK + lk];
                short8 kf1 = *(const short8*)&Kt[(n * 16 + lr) * DK + 32 + lk];
                st[n] = __builtin_amdgcn_mfma_f32_16x16x32_bf16(kf0, qf0, st[n], 0, 0, 0);
                st[n] = __builtin_amdgcn_mfma_f32_16x16x32_bf16(kf1, qf1, st[n], 0, 0, 0);
            }
        }
        __builtin_amdgcn_s_setprio(0);

        if (diag) {   // causal mask within diagonal tile
#pragma unroll
            for (int n = 0; n < 4; n++)
#pragma unroll
                for (int i = 0; i < 4; i++)
                    if (16 * n + r0 + i > wq) st[n][i] = -1e30f;
        }

        // per-lane softmax (q = lr), reduce across 4 lane-groups
        float m0 = fmaxf(fmaxf(fmaxf(st[0][0], st[0][1]), st[0][2]), st[0][3]);
        float m1 = fmaxf(fmaxf(fmaxf(st[1][0], st[1][1]), st[1][2]), st[1][3]);
        float m2 = fmaxf(fmaxf(fmaxf(st[2][0], st[2][1]), st[2][2]), st[2][3]);
        float m3 = fmaxf(fmaxf(fmaxf(st[3][0], st[3][1]), st[3][2]), st[3][3]);
        float mx = fmaxf(fmaxf(fmaxf(m0, m1), m2), m3);
        float mxL = red_max4(mx) * CSC;

        bool skip = __all(mxL <= mrowL + 8.0f);   // T13 defer-max
        float corr = 1.0f;
        float mnewL = mrowL;
        if (!skip) {
            mnewL = fmaxf(mrowL, mxL);
            corr = fexp2(mrowL - mnewL);
            mrowL = mnewL;
        }

        float psum = 0.f;
        uint32_t wp[4][2];
#pragma unroll
        for (int n = 0; n < 4; n++) {
#pragma unroll
            for (int i = 0; i < 4; i++) {
                float p = fexp2(fmaf(st[n][i], CSC, -mnewL));
                st[n][i] = p;
                psum += p;
            }
            wp[n][0] = (uint32_t)bfc(st[n][0]) | ((uint32_t)bfc(st[n][1]) << 16);
            wp[n][1] = (uint32_t)bfc(st[n][2]) | ((uint32_t)bfc(st[n][3]) << 16);
        }
        psum = red_sum4(psum);

        if (skip) {
            lrow += psum;
        } else {
            lrow = lrow * corr + psum;
            float cb[4];
#pragma unroll
            for (int i = 0; i < 4; i++) cb[i] = __shfl(corr, r0 + i);
#pragma unroll
            for (int d = 0; d < 4; d++)
#pragma unroll
                for (int i = 0; i < 4; i++) o[d][i] *= cb[i];
        }

        // PV: O += P V, P frags routed in-register, V frags from regs
#pragma unroll
        for (int ks = 0; ks < 2; ks++) {
            if (diag && 32 * ks > w * 16 + 15) continue;  // slice fully masked
            uint32_t F[4];
            route_p(wp, ks, lane, F);
            union { uint32_t u[4]; short8 s; } pu;
            pu.u[0] = F[0]; pu.u[1] = F[1]; pu.u[2] = F[2]; pu.u[3] = F[3];
            short8 pf = pu.s;
            __builtin_amdgcn_s_setprio(1);
#pragma unroll
            for (int d = 0; d < 4; d++)
                o[d] = __builtin_amdgcn_mfma_f32_16x16x32_bf16(pf, vf[d][ks], o[d], 0, 0, 0);
            __builtin_amdgcn_s_setprio(0);
        }
    }

    // epilogue
    int b = bh >> 4, h = bh & 15;
    if (kk == 9) {
        // single chunk: normalize and write final bf16
        float lb[4];
#pragma unroll
        for (int i = 0; i < 4; i++) lb[i] = frcp(__shfl(lrow, r0 + i));
#pragma unroll
        for (int d = 0; d < 4; d++)
#pragma unroll
            for (int i = 0; i < 4; i++) {
                int qq = q0 + w * 16 + r0 + i;
                int dk = d * 16 + lr;
                size_t idx = ((size_t)(b * S_LEN + qq)) * D_DIM + h * DK + dk;
                Oa[idx] = bfc(o[d][i] * lb[i]);
            }
    } else {
        int jj = j - 16;
        if (kk == 0) {
            // chunk0 partial: unnormalized bf16 into the final O slot
#pragma unroll
            for (int d = 0; d < 4; d++)
#pragma unroll
                for (int i = 0; i < 4; i++) {
                    int qq = q0 + w * 16 + r0 + i;
                    int dk = d * 16 + lr;
                    size_t idx = ((size_t)(b * S_LEN + qq)) * D_DIM + h * DK + dk;
                    Oa[idx] = bfc(o[d][i]);
                }
        } else {
            // chunk1 partial: f32 into Pd scratch (d_out)
#pragma unroll
            for (int d = 0; d < 4; d++)
#pragma unroll
                for (int i = 0; i < 4; i++) {
                    int rloc = w * 16 + r0 + i;
                    Pd[((size_t)(bh * 16 + jj) * 64 + rloc) * 64 + d * 16 + lr] = o[d][i];
                }
        }
        if (lane < 16) {
            int row = w * 16 + lane;   // lanes 0..15 hold rows (q=lr) stats
            ml[(size_t)kk * 32768 + (bh * 16 + jj) * 64 + row] = make_float2(mrowL, lrow);
        }
    }
}

// ---------------- merge of split-tile partials ----------------
__global__ __launch_bounds__(256) void attn_merge(const float2* __restrict__ ml,
                                                  const float* __restrict__ Pd,
                                                  ushort_t* __restrict__ Oa) {
    int bh = blockIdx.x;           // 0..31
    int jj = blockIdx.y;           // 0..15 -> j = jj+16
    int tid = threadIdx.x;
    int r = tid >> 2;              // row 0..63
    int q = (tid & 3) * 16;        // dk start
    int b = bh >> 4, h = bh & 15;
    int row = (jj + 16) * 64 + r;
    float2 a = ml[(bh * 16 + jj) * 64 + r];
    float2 c = ml[32768 + (bh * 16 + jj) * 64 + r];
    float M = fmaxf(a.x, c.x);
    float w0 = fexp2(a.x - M), w1 = fexp2(c.x - M);
    float rc = frcp(a.y * w0 + c.y * w1);
    size_t ob = ((size_t)(b * S_LEN + row)) * D_DIM + h * DK + q;
    const float* p1 = &Pd[((size_t)(bh * 16 + jj) * 64 + r) * 64 + q];
#pragma unroll
    for (int i = 0; i < 4; i++) {
        ushort4 o0 = *(const ushort4*)&Oa[ob + i * 4];
        float4 o1 = *(const float4*)&p1[i * 4];
        ushort4 res;
        res.x = bfc((bf2f(o0.x) * w0 + o1.x * w1) * rc);
        res.y = bfc((bf2f(o0.y) * w0 + o1.y * w1) * rc);
        res.z = bfc((bf2f(o0.z) * w0 + o1.z * w1) * rc);
        res.w = bfc((bf2f(o0.w) * w0 + o1.w * w1) * rc);
        *(ushort4*)&Oa[ob + i * 4] = res;
    }
}

// ---------------- launch ----------------
extern "C" void kernel_launch(void* const* d_in, const int* in_sizes, int n_in,
                              void* d_out, int out_size, void* d_ws, size_t ws_size,
                              hipStream_t stream) {
    const float* X  = (const float*)d_in[0];
    const float* Wq = (const float*)d_in[1];
    const float* bq = (const float*)d_in[2];
    const float* Wk = (const float*)d_in[3];
    const float* bk = (const float*)d_in[4];
    const float* Wv = (const float*)d_in[5];
    const float* bv = (const float*)d_in[6];
    const float* Wo = (const float*)d_in[7];
    const float* bo = (const float*)d_in[8];
    float* out = (float*)d_out;

    char* ws = (char*)d_ws;
    ushort_t* Xb    = (ushort_t*)ws;                        // 8 MiB [M,D] bf16 (later: attn out)
    ushort_t* Wqkvb = (ushort_t*)(ws + (8u  << 20));        // 6 MiB; dead after QKV gemm
    float2*   mlbuf = (float2*)(ws + (8u  << 20));          // 0.5 MiB (over dead Wqkvb)
    ushort_t* Qb    = (ushort_t*)(ws + (14u << 20));        // 8 MiB [b,h,s,dk]
    ushort_t* Kb    = (ushort_t*)(ws + (22u << 20));        // 8 MiB [b,h,s,dk]
    ushort_t* Vtb   = (ushort_t*)(ws + (30u << 20));        // 8 MiB [b,h,dk,s]
    ushort_t* Wob   = Wqkvb;                                // reuse after merge
    ushort_t* Ab    = Xb;                                   // attn out reuses X slot
    float*    Pd    = out;                                  // chunk1 partials scratch (dead until Wo gemm)

    const int M = M_ROWS;
    int nX4 = (M * D_DIM) / 4;
    int nW4 = (D_DIM * D_DIM) / 4;

    cvt_bf16<<<2048, 256, 0, stream>>>(X, Xb, nX4);
    cvt_w3<<<2048, 256, 0, stream>>>(Wq, Wk, Wv, Wqkvb);

    // fused QKV: 32 x 24 = 768 blocks (3/CU)
    gemm_bt<3, 128, 128><<<dim3((M / 128) * (3072 / 128)), 256, 0, stream>>>(
        Xb, Wqkvb, bq, bk, bv, Qb, Kb, Vtb, M, 3072, D_DIM);

    // attn: 32 x 48 chunk-blocks, snake-balanced + staggered, LDS-free
    dim3 agrid(BATCH * NH, 48);
    attn_fwd<<<agrid, 256, 0, stream>>>(Qb, Kb, Vtb, Ab, mlbuf, Pd);

    // merge split-tile partials (reads Pd + Ab partials, finalizes Ab)
    attn_merge<<<dim3(BATCH * NH, 16), 256, 0, stream>>>(mlbuf, Pd, Ab);

    cvt_bf16<<<2048, 256, 0, stream>>>(Wo, Wob, nW4);   // after merge (overlays mlbuf)

    // Wo gemm: 64x128 tiles -> 512 blocks (2/CU); overwrites all of d_out
    gemm_bt<2, 64, 128><<<dim3((M / 64) * (D_DIM / 128)), 256, 0, stream>>>(
        Ab, Wob, bo, bo, bo, out, out, out, M, D_DIM, D_DIM);
}

// Round 11
// 139.171 us; speedup vs baseline: 1.5497x; 1.5497x over previous
//
#include <hip/hip_runtime.h>
#include <hip/hip_bf16.h>
#include <cstdint>

typedef __attribute__((ext_vector_type(8))) short short8;
typedef __attribute__((ext_vector_type(4))) float f32x4;
typedef __attribute__((ext_vector_type(2))) unsigned int uint2v;
typedef unsigned short ushort_t;

#define S_LEN 2048
#define D_DIM 1024
#define NH 16
#define DK 64
#define BATCH 2
#define M_ROWS (BATCH * S_LEN)   // 4096
#define BK 32

__device__ inline ushort_t f2bf(float f) {
    union { float f; uint32_t u; } v; v.f = f;
    uint32_t r = v.u + 0x7fffu + ((v.u >> 16) & 1u);  // RNE
    return (ushort_t)(r >> 16);
}

__device__ __forceinline__ ushort_t bfc(float f) {
    __hip_bfloat16 h = __float2bfloat16(f);          // HW cvt path
    return __builtin_bit_cast(ushort_t, h);
}

__device__ __forceinline__ float bf2f(ushort_t u) {
    return __uint_as_float(((uint32_t)u) << 16);
}

// HW transcendentals (OCML exp2f/div are multi-instruction without fast-math)
__device__ __forceinline__ float fexp2(float x) {
#if __has_builtin(__builtin_amdgcn_exp2f)
    return __builtin_amdgcn_exp2f(x);
#else
    return exp2f(x);
#endif
}
__device__ __forceinline__ float frcp(float x) {
#if __has_builtin(__builtin_amdgcn_rcpf)
    return __builtin_amdgcn_rcpf(x);
#else
    return 1.0f / x;
#endif
}

__device__ __forceinline__ void glds16(const ushort_t* g, ushort_t* l) {
    __builtin_amdgcn_global_load_lds(
        (const __attribute__((address_space(1))) uint32_t*)g,
        (__attribute__((address_space(3))) uint32_t*)l,
        16, 0, 0);
}

#if __has_builtin(__builtin_amdgcn_permlane16_swap) && __has_builtin(__builtin_amdgcn_permlane32_swap)
#define HAS_PLSWAP 1
#else
#define HAS_PLSWAP 0
#endif

// cross-lane reduce over the 4 16-lane groups (lanes l, l^16, l^32, l^48)
__device__ __forceinline__ float red_max4(float x) {
#if HAS_PLSWAP
    uint2v a = __builtin_amdgcn_permlane16_swap(__float_as_uint(x), __float_as_uint(x), false, false);
    float y = fmaxf(__uint_as_float(a.x), __uint_as_float(a.y));
    uint2v b = __builtin_amdgcn_permlane32_swap(__float_as_uint(y), __float_as_uint(y), false, false);
    return fmaxf(__uint_as_float(b.x), __uint_as_float(b.y));
#else
    x = fmaxf(x, __shfl_xor(x, 16));
    return fmaxf(x, __shfl_xor(x, 32));
#endif
}
__device__ __forceinline__ float red_sum4(float x) {
#if HAS_PLSWAP
    uint2v a = __builtin_amdgcn_permlane16_swap(__float_as_uint(x), __float_as_uint(x), false, false);
    float y = __uint_as_float(a.x) + __uint_as_float(a.y);
    uint2v b = __builtin_amdgcn_permlane32_swap(__float_as_uint(y), __float_as_uint(y), false, false);
    return __uint_as_float(b.x) + __uint_as_float(b.y);
#else
    x += __shfl_xor(x, 16);
    return x + __shfl_xor(x, 32);
#endif
}

// T12 route: build PV A-frag words F[0..3] for k-slice ks from packed P words
// wp[n][h] (kv = 16n + 4*(lane>>4) + 2h + {0,1}, q = lane&15).
__device__ __forceinline__ void route_p(const uint32_t wp[4][2], int ks, int lane, uint32_t F[4]) {
#if HAS_PLSWAP
    uint32_t U0 = wp[2 * ks][0],     U1 = wp[2 * ks][1];
    uint32_t V0 = wp[2 * ks + 1][0], V1 = wp[2 * ks + 1][1];
    uint2v t, pa0, pa1, pb0, pb1;
    t = __builtin_amdgcn_permlane32_swap(U0, U0, false, false);
    pa0 = __builtin_amdgcn_permlane16_swap(U0, t.y, false, false);
    t = __builtin_amdgcn_permlane32_swap(U1, U1, false, false);
    pa1 = __builtin_amdgcn_permlane16_swap(U1, t.y, false, false);
    t = __builtin_amdgcn_permlane32_swap(V0, V0, false, false);
    pb0 = __builtin_amdgcn_permlane16_swap(t.x, V0, false, false);
    t = __builtin_amdgcn_permlane32_swap(V1, V1, false, false);
    pb1 = __builtin_amdgcn_permlane16_swap(t.x, V1, false, false);
    bool lo = lane < 32;
    F[0] = lo ? pa0.x : pb0.x;
    F[1] = lo ? pa1.x : pb1.x;
    F[2] = lo ? pa0.y : pb0.y;
    F[3] = lo ? pa1.y : pb1.y;
#else
    int q = lane & 15, g = lane >> 4;
#pragma unroll
    for (int m = 0; m < 4; m++) {
        int src = 16 * (2 * (g & 1) + (m >> 1)) + q;
        uint32_t xa = (uint32_t)__shfl((int)wp[2 * ks][m & 1], src);
        uint32_t xb = (uint32_t)__shfl((int)wp[2 * ks + 1][m & 1], src);
        F[m] = (g < 2) ? xa : xb;
    }
#endif
}

// ---------------- fp32 -> bf16 convert (vectorized) ----------------
__global__ void cvt_bf16(const float* __restrict__ in, ushort_t* __restrict__ out, int n4) {
    int i = blockIdx.x * blockDim.x + threadIdx.x;
    int stride = gridDim.x * blockDim.x;
    for (int idx = i; idx < n4; idx += stride) {
        float4 v = ((const float4*)in)[idx];
        ushort4 o;
        o.x = f2bf(v.x); o.y = f2bf(v.y); o.z = f2bf(v.z); o.w = f2bf(v.w);
        ((ushort4*)out)[idx] = o;
    }
}

// fused convert of Wq,Wk,Wv into one [3072,1024] bf16 buffer
__global__ void cvt_w3(const float* __restrict__ wq, const float* __restrict__ wk,
                       const float* __restrict__ wv, ushort_t* __restrict__ wqkv) {
    const int seg = (D_DIM * D_DIM) / 4;   // 2^18
    int i = blockIdx.x * blockDim.x + threadIdx.x;
    int stride = gridDim.x * blockDim.x;
    for (int idx = i; idx < 3 * seg; idx += stride) {
        int sel = idx >> 18;
        int id = idx & (seg - 1);
        const float* src = sel == 0 ? wq : (sel == 1 ? wk : wv);
        float4 v = ((const float4*)src)[id];
        ushort4 o;
        o.x = f2bf(v.x); o.y = f2bf(v.y); o.z = f2bf(v.z); o.w = f2bf(v.w);
        ((ushort4*)wqkv)[sel * seg + id] = o;
    }
}

// ---------------- GEMM: C = A[M,K] * Bw[N,K]^T + bias ----------------
// T1: bijective XCD remap (grid must be a multiple of 8 blocks).
template<int MODE, int BMt, int BNt>
__global__ __launch_bounds__(256) void gemm_bt(const ushort_t* __restrict__ A,
                                               const ushort_t* __restrict__ Bw,
                                               const float* __restrict__ b0,
                                               const float* __restrict__ b1,
                                               const float* __restrict__ b2,
                                               void* __restrict__ C0,
                                               void* __restrict__ C1,
                                               void* __restrict__ C2,
                                               int M, int N, int K) {
    constexpr int FM = BMt / 32, FN = BNt / 32;
    constexpr int ACH = BMt / 64, BCH = BNt / 64;
    __shared__ ushort_t As[BMt * BK];
    __shared__ ushort_t Bs[BNt * BK];
    int tid = threadIdx.x;
    int lane = tid & 63;
    int w = tid >> 6;
    int wr = w >> 1, wc = w & 1;
    // XCD-aware remap: consecutive logical tiles (same A panel) -> same XCD L2
    int nwg = gridDim.x;
    int bx = (blockIdx.x & 7) * (nwg >> 3) + (blockIdx.x >> 3);
    int ntile = N / BNt;
    int m0 = (bx / ntile) * BMt;
    int n0 = (bx % ntile) * BNt;
    int lr = lane & 15;
    int lk = (lane >> 4) * 8;
    int srow = lane >> 2;            // 0..15
    int scol = (lane & 3) * 8;

    f32x4 acc[FM][FN] = {};

    for (int kt = 0; kt < K; kt += BK) {
        __syncthreads();
#pragma unroll
        for (int c = 0; c < ACH; c++)
            glds16(&A[(size_t)(m0 + w * (BMt / 4) + c * 16 + srow) * K + kt + scol],
                   &As[(w * (BMt / 4) + c * 16) * BK]);
#pragma unroll
        for (int c = 0; c < BCH; c++)
            glds16(&Bw[(size_t)(n0 + w * (BNt / 4) + c * 16 + srow) * K + kt + scol],
                   &Bs[(w * (BNt / 4) + c * 16) * BK]);
        __syncthreads();

        short8 af[FM], bf[FN];
#pragma unroll
        for (int f = 0; f < FM; f++)
            af[f] = *(const short8*)&As[(wr * (BMt / 2) + f * 16 + lr) * BK + lk];
#pragma unroll
        for (int f = 0; f < FN; f++)
            bf[f] = *(const short8*)&Bs[(wc * (BNt / 2) + f * 16 + lr) * BK + lk];
#pragma unroll
        for (int i = 0; i < FM; i++)
#pragma unroll
            for (int j = 0; j < FN; j++)
                acc[i][j] = __builtin_amdgcn_mfma_f32_16x16x32_bf16(af[i], bf[j], acc[i][j], 0, 0, 0);
    }

    int r0 = (lane >> 4) * 4;
#pragma unroll
    for (int j = 0; j < FN; j++) {
        int ncol = n0 + wc * (BNt / 2) + j * 16 + lr;
        if (MODE == 2) {
            float bv = b0[ncol];
#pragma unroll
            for (int i = 0; i < FM; i++) {
                int mbase = m0 + wr * (BMt / 2) + i * 16 + r0;
#pragma unroll
                for (int r = 0; r < 4; r++)
                    ((float*)C0)[(size_t)(mbase + r) * N + ncol] = acc[i][j][r] + bv;
            }
        } else {
            int sel = n0 >> 10;                    // block-uniform
            const float* bp = sel == 0 ? b0 : (sel == 1 ? b1 : b2);
            int nc = ncol & 1023;
            float bv = bp[nc];
            int hh = nc >> 6, dk = nc & 63;
            ushort_t* Co = (ushort_t*)(sel == 0 ? C0 : (sel == 1 ? C1 : C2));
#pragma unroll
            for (int i = 0; i < FM; i++) {
                int mbase = m0 + wr * (BMt / 2) + i * 16 + r0;
                int bb = mbase >> 11, ss = mbase & 2047;
                if (sel == 2) {
                    ushort4 pk;
                    pk.x = f2bf(acc[i][j][0] + bv);
                    pk.y = f2bf(acc[i][j][1] + bv);
                    pk.z = f2bf(acc[i][j][2] + bv);
                    pk.w = f2bf(acc[i][j][3] + bv);
                    size_t idx = ((size_t)(bb * NH + hh) * DK + dk) * S_LEN + ss;
                    *(ushort4*)&Co[idx] = pk;
                } else {
#pragma unroll
                    for (int r = 0; r < 4; r++) {
                        size_t idx = ((size_t)(bb * NH + hh) * S_LEN + (ss + r)) * DK + dk;
                        Co[idx] = f2bf(acc[i][j][r] + bv);
                    }
                }
            }
        }
    }
}

// ---------------- Flash attention (causal, kv-split, cross-tile pipelined) ----------------
// Round-9 base (LDS dbuf, snake table, stagger) + software pipeline:
// iteration s issues QK^T of tile ord(s+1) (MFMA, results used next iter)
// then runs softmax+PV of tile ord(s) (VALU/MFMA on registers) -> the two
// overlap within each wave. V frags move LDS->regs right after the publish
// barrier, so each LDS buffer's reads cluster immediately after its write:
// 2 buffers / 1 barrier per tile stays race-free.
#define CSC 0.1803368801f   // 0.125 * log2(e)

__device__ const unsigned char JTAB[48] = {
    30,31,31,15,28,29,29,30,
    25,24,13,28,27,27,26,14,
    25,26,12,22,23,23,24,11,
    19,19,18,10,22,21,21,20,
    20, 9,16,17,17,18, 8,16,
     0, 1, 2, 3, 4, 5, 6, 7};
__device__ const unsigned char KTAB[48] = {
     0, 0, 1, 9, 0, 0, 1, 1,
     0, 0, 9, 1, 1, 0, 0, 9,
     1, 1, 9, 0, 0, 1, 1, 9,
     1, 0, 0, 9, 1, 1, 0, 0,
     1, 9, 0, 0, 1, 1, 9, 1,
     9, 9, 9, 9, 9, 9, 9, 9};

__global__ __launch_bounds__(256) void attn_fwd(const ushort_t* __restrict__ Q,
                                                const ushort_t* __restrict__ K,
                                                const ushort_t* __restrict__ Vt,
                                                ushort_t* __restrict__ Oa,
                                                float2* __restrict__ ml,
                                                float* __restrict__ Pd) {
    __shared__ ushort_t Ks[2][64 * 64];
    __shared__ ushort_t Vs[2][64 * 64];

    int tid = threadIdx.x;
    int lane = tid & 63;
    int w = tid >> 6;
    int bh = blockIdx.x;           // 0..31
    int yy = blockIdx.y;           // 0..47
    int j = JTAB[yy];
    int kk = KTAB[yy];             // 0/1 = split chunk, 9 = single
    int nt = j + 1;
    int half = (nt + 1) >> 1;
    int t0 = (kk == 1) ? half : 0;
    int t1 = (kk == 0) ? half : nt;
    int cnt = t1 - t0;
    int off = yy % cnt;            // per-block stagger (same-CU mates differ)
    size_t base = (size_t)bh * S_LEN * DK;
    int q0 = j * 64;

    int lr = lane & 15;
    int lk = (lane >> 4) * 8;
    int g16 = (lane >> 4) * 16;    // byte col of fragment k-slice
    int r0 = (lane >> 4) * 4;
    int wq = w * 16 + lr;          // this lane's q row (within tile)

    // XOR swizzle: ushort index for (row, byte-col) in a [64][128B] tile
    auto swz = [](int row, int cb) { return (row * 128 + (cb ^ ((row & 7) << 4))) >> 1; };

    // Q fragment (16 rows per wave)
    short8 qf0 = *(const short8*)&Q[base + (size_t)(q0 + wq) * DK + lk];
    short8 qf1 = *(const short8*)&Q[base + (size_t)(q0 + wq) * DK + 32 + lk];

    f32x4 o[4] = {};
    float mrowL = -1e30f, lrow = 0.f;

    int sr = tid >> 3;            // 0..31
    int scb = (tid & 7) * 16;     // byte col
    int sce = (tid & 7) * 8;      // element col

    // prologue: stage ord(0) into LDS[0]; prefetch ord(1) into gregs
    int tc = t0 + off;            // ord(0)
    *(uint4*)&Ks[0][swz(sr, scb)]      = *(const uint4*)&K [base + (size_t)(tc * 64 + sr) * DK + sce];
    *(uint4*)&Ks[0][swz(sr + 32, scb)] = *(const uint4*)&K [base + (size_t)(tc * 64 + sr + 32) * DK + sce];
    *(uint4*)&Vs[0][swz(sr, scb)]      = *(const uint4*)&Vt[base + (size_t)sr * S_LEN + tc * 64 + sce];
    *(uint4*)&Vs[0][swz(sr + 32, scb)] = *(const uint4*)&Vt[base + (size_t)(sr + 32) * S_LEN + tc * 64 + sce];
    uint4 kr0, kr1, vr0, vr1;
    if (cnt > 1) {
        int to = 1 + off; if (to >= cnt) to -= cnt;
        int tn = t0 + to;
        kr0 = *(const uint4*)&K [base + (size_t)(tn * 64 + sr) * DK + sce];
        kr1 = *(const uint4*)&K [base + (size_t)(tn * 64 + sr + 32) * DK + sce];
        vr0 = *(const uint4*)&Vt[base + (size_t)sr * S_LEN + tn * 64 + sce];
        vr1 = *(const uint4*)&Vt[base + (size_t)(sr + 32) * S_LEN + tn * 64 + sce];
    }
    __syncthreads();

    // QK(ord0) + V frags -> regs (current-tile state)
    bool diagc = (tc == j);
    f32x4 stc[4] = {};
    short8 vfc[4][2];
    __builtin_amdgcn_s_setprio(1);
#pragma unroll
    for (int n = 0; n < 4; n++) {
        if (!diagc || n <= w) {
            short8 kf0 = *(const short8*)&Ks[0][swz(n * 16 + lr, g16)];
            short8 kf1 = *(const short8*)&Ks[0][swz(n * 16 + lr, 64 + g16)];
            stc[n] = __builtin_amdgcn_mfma_f32_16x16x32_bf16(kf0, qf0, stc[n], 0, 0, 0);
            stc[n] = __builtin_amdgcn_mfma_f32_16x16x32_bf16(kf1, qf1, stc[n], 0, 0, 0);
        }
    }
    __builtin_amdgcn_s_setprio(0);
#pragma unroll
    for (int ks = 0; ks < 2; ks++)
        if (!diagc || 32 * ks <= w * 16 + 15)
#pragma unroll
            for (int d = 0; d < 4; d++)
                vfc[d][ks] = *(const short8*)&Vs[0][swz(d * 16 + lr, ks * 64 + g16)];

    for (int s = 0; s < cnt; ++s) {
        // ---- issue next tile: publish LDS, QK MFMAs (results used next iter) ----
        f32x4 stn[4] = {};
        short8 vfn[4][2];
        bool diagn = false;
        int tnn = tc;
        if (s + 1 < cnt) {
            int b1 = (s + 1) & 1;
            *(uint4*)&Ks[b1][swz(sr, scb)]      = kr0;
            *(uint4*)&Ks[b1][swz(sr + 32, scb)] = kr1;
            *(uint4*)&Vs[b1][swz(sr, scb)]      = vr0;
            *(uint4*)&Vs[b1][swz(sr + 32, scb)] = vr1;
            __syncthreads();
            int to = s + 1 + off; if (to >= cnt) to -= cnt;
            tnn = t0 + to;
            diagn = (tnn == j);
            __builtin_amdgcn_s_setprio(1);
#pragma unroll
            for (int n = 0; n < 4; n++) {
                if (!diagn || n <= w) {
                    short8 kf0 = *(const short8*)&Ks[b1][swz(n * 16 + lr, g16)];
                    short8 kf1 = *(const short8*)&Ks[b1][swz(n * 16 + lr, 64 + g16)];
                    stn[n] = __builtin_amdgcn_mfma_f32_16x16x32_bf16(kf0, qf0, stn[n], 0, 0, 0);
                    stn[n] = __builtin_amdgcn_mfma_f32_16x16x32_bf16(kf1, qf1, stn[n], 0, 0, 0);
                }
            }
            __builtin_amdgcn_s_setprio(0);
#pragma unroll
            for (int ks = 0; ks < 2; ks++)
                if (!diagn || 32 * ks <= w * 16 + 15)
#pragma unroll
                    for (int d = 0; d < 4; d++)
                        vfn[d][ks] = *(const short8*)&Vs[b1][swz(d * 16 + lr, ks * 64 + g16)];
            if (s + 2 < cnt) {
                int to2 = s + 2 + off; if (to2 >= cnt) to2 -= cnt;
                int tn2 = t0 + to2;
                kr0 = *(const uint4*)&K [base + (size_t)(tn2 * 64 + sr) * DK + sce];
                kr1 = *(const uint4*)&K [base + (size_t)(tn2 * 64 + sr + 32) * DK + sce];
                vr0 = *(const uint4*)&Vt[base + (size_t)sr * S_LEN + tn2 * 64 + sce];
                vr1 = *(const uint4*)&Vt[base + (size_t)(sr + 32) * S_LEN + tn2 * 64 + sce];
            }
        }

        // ---- finish current tile tc: softmax + PV (round-9 machinery) ----
        if (diagc) {   // causal mask within diagonal tile
#pragma unroll
            for (int n = 0; n < 4; n++)
#pragma unroll
                for (int i = 0; i < 4; i++)
                    if (16 * n + r0 + i > wq) stc[n][i] = -1e30f;
        }

        float m0 = fmaxf(fmaxf(fmaxf(stc[0][0], stc[0][1]), stc[0][2]), stc[0][3]);
        float m1 = fmaxf(fmaxf(fmaxf(stc[1][0], stc[1][1]), stc[1][2]), stc[1][3]);
        float m2 = fmaxf(fmaxf(fmaxf(stc[2][0], stc[2][1]), stc[2][2]), stc[2][3]);
        float m3 = fmaxf(fmaxf(fmaxf(stc[3][0], stc[3][1]), stc[3][2]), stc[3][3]);
        float mx = fmaxf(fmaxf(fmaxf(m0, m1), m2), m3);
        float mxL = red_max4(mx) * CSC;

        bool skip = __all(mxL <= mrowL + 8.0f);   // T13 defer-max
        float corr = 1.0f;
        float mnewL = mrowL;
        if (!skip) {
            mnewL = fmaxf(mrowL, mxL);
            corr = fexp2(mrowL - mnewL);
            mrowL = mnewL;
        }

        float psum = 0.f;
        uint32_t wp[4][2];
#pragma unroll
        for (int n = 0; n < 4; n++) {
#pragma unroll
            for (int i = 0; i < 4; i++) {
                float p = fexp2(fmaf(stc[n][i], CSC, -mnewL));
                stc[n][i] = p;
                psum += p;
            }
            wp[n][0] = (uint32_t)bfc(stc[n][0]) | ((uint32_t)bfc(stc[n][1]) << 16);
            wp[n][1] = (uint32_t)bfc(stc[n][2]) | ((uint32_t)bfc(stc[n][3]) << 16);
        }
        psum = red_sum4(psum);

        if (skip) {
            lrow += psum;
        } else {
            lrow = lrow * corr + psum;
            float cb[4];
#pragma unroll
            for (int i = 0; i < 4; i++) cb[i] = __shfl(corr, r0 + i);
#pragma unroll
            for (int d = 0; d < 4; d++)
#pragma unroll
                for (int i = 0; i < 4; i++) o[d][i] *= cb[i];
        }

        // PV: O += P V, P routed in-register, V from regs
#pragma unroll
        for (int ks = 0; ks < 2; ks++) {
            if (diagc && 32 * ks > w * 16 + 15) continue;  // slice fully masked
            uint32_t F[4];
            route_p(wp, ks, lane, F);
            union { uint32_t u[4]; short8 s; } pu;
            pu.u[0] = F[0]; pu.u[1] = F[1]; pu.u[2] = F[2]; pu.u[3] = F[3];
            short8 pf = pu.s;
            __builtin_amdgcn_s_setprio(1);
#pragma unroll
            for (int d = 0; d < 4; d++)
                o[d] = __builtin_amdgcn_mfma_f32_16x16x32_bf16(pf, vfc[d][ks], o[d], 0, 0, 0);
            __builtin_amdgcn_s_setprio(0);
        }

        // ---- advance pipeline state (named copies, compile-time indices) ----
#pragma unroll
        for (int n = 0; n < 4; n++) stc[n] = stn[n];
#pragma unroll
        for (int ks = 0; ks < 2; ks++)
#pragma unroll
            for (int d = 0; d < 4; d++) vfc[d][ks] = vfn[d][ks];
        tc = tnn;
        diagc = diagn;
    }

    // epilogue
    int b = bh >> 4, h = bh & 15;
    if (kk == 9) {
        // single chunk: normalize and write final bf16
        float lb[4];
#pragma unroll
        for (int i = 0; i < 4; i++) lb[i] = frcp(__shfl(lrow, r0 + i));
#pragma unroll
        for (int d = 0; d < 4; d++)
#pragma unroll
            for (int i = 0; i < 4; i++) {
                int qq = q0 + w * 16 + r0 + i;
                int dk = d * 16 + lr;
                size_t idx = ((size_t)(b * S_LEN + qq)) * D_DIM + h * DK + dk;
                Oa[idx] = bfc(o[d][i] * lb[i]);
            }
    } else {
        int jj = j - 16;
        if (kk == 0) {
            // chunk0 partial: unnormalized bf16 into the final O slot
#pragma unroll
            for (int d = 0; d < 4; d++)
#pragma unroll
                for (int i = 0; i < 4; i++) {
                    int qq = q0 + w * 16 + r0 + i;
                    int dk = d * 16 + lr;
                    size_t idx = ((size_t)(b * S_LEN + qq)) * D_DIM + h * DK + dk;
                    Oa[idx] = bfc(o[d][i]);
                }
        } else {
            // chunk1 partial: f32 into Pd scratch (d_out)
#pragma unroll
            for (int d = 0; d < 4; d++)
#pragma unroll
                for (int i = 0; i < 4; i++) {
                    int rloc = w * 16 + r0 + i;
                    Pd[((size_t)(bh * 16 + jj) * 64 + rloc) * 64 + d * 16 + lr] = o[d][i];
                }
        }
        if (lane < 16) {
            int row = w * 16 + lane;   // lanes 0..15 hold rows (q=lr) stats
            ml[(size_t)kk * 32768 + (bh * 16 + jj) * 64 + row] = make_float2(mrowL, lrow);
        }
    }
}

// ---------------- merge of split-tile partials ----------------
__global__ __launch_bounds__(256) void attn_merge(const float2* __restrict__ ml,
                                                  const float* __restrict__ Pd,
                                                  ushort_t* __restrict__ Oa) {
    int bh = blockIdx.x;           // 0..31
    int jj = blockIdx.y;           // 0..15 -> j = jj+16
    int tid = threadIdx.x;
    int r = tid >> 2;              // row 0..63
    int q = (tid & 3) * 16;        // dk start
    int b = bh >> 4, h = bh & 15;
    int row = (jj + 16) * 64 + r;
    float2 a = ml[(bh * 16 + jj) * 64 + r];
    float2 c = ml[32768 + (bh * 16 + jj) * 64 + r];
    float M = fmaxf(a.x, c.x);
    float w0 = fexp2(a.x - M), w1 = fexp2(c.x - M);
    float rc = frcp(a.y * w0 + c.y * w1);
    size_t ob = ((size_t)(b * S_LEN + row)) * D_DIM + h * DK + q;
    const float* p1 = &Pd[((size_t)(bh * 16 + jj) * 64 + r) * 64 + q];
#pragma unroll
    for (int i = 0; i < 4; i++) {
        ushort4 o0 = *(const ushort4*)&Oa[ob + i * 4];
        float4 o1 = *(const float4*)&p1[i * 4];
        ushort4 res;
        res.x = bfc((bf2f(o0.x) * w0 + o1.x * w1) * rc);
        res.y = bfc((bf2f(o0.y) * w0 + o1.y * w1) * rc);
        res.z = bfc((bf2f(o0.z) * w0 + o1.z * w1) * rc);
        res.w = bfc((bf2f(o0.w) * w0 + o1.w * w1) * rc);
        *(ushort4*)&Oa[ob + i * 4] = res;
    }
}

// ---------------- launch ----------------
extern "C" void kernel_launch(void* const* d_in, const int* in_sizes, int n_in,
                              void* d_out, int out_size, void* d_ws, size_t ws_size,
                              hipStream_t stream) {
    const float* X  = (const float*)d_in[0];
    const float* Wq = (const float*)d_in[1];
    const float* bq = (const float*)d_in[2];
    const float* Wk = (const float*)d_in[3];
    const float* bk = (const float*)d_in[4];
    const float* Wv = (const float*)d_in[5];
    const float* bv = (const float*)d_in[6];
    const float* Wo = (const float*)d_in[7];
    const float* bo = (const float*)d_in[8];
    float* out = (float*)d_out;

    char* ws = (char*)d_ws;
    ushort_t* Xb    = (ushort_t*)ws;                        // 8 MiB [M,D] bf16 (later: attn out)
    ushort_t* Wqkvb = (ushort_t*)(ws + (8u  << 20));        // 6 MiB; dead after QKV gemm
    float2*   mlbuf = (float2*)(ws + (8u  << 20));          // 0.5 MiB (over dead Wqkvb)
    ushort_t* Qb    = (ushort_t*)(ws + (14u << 20));        // 8 MiB [b,h,s,dk]
    ushort_t* Kb    = (ushort_t*)(ws + (22u << 20));        // 8 MiB [b,h,s,dk]
    ushort_t* Vtb   = (ushort_t*)(ws + (30u << 20));        // 8 MiB [b,h,dk,s]
    ushort_t* Wob   = Wqkvb;                                // reuse after merge
    ushort_t* Ab    = Xb;                                   // attn out reuses X slot
    float*    Pd    = out;                                  // chunk1 partials scratch (dead until Wo gemm)

    const int M = M_ROWS;
    int nX4 = (M * D_DIM) / 4;
    int nW4 = (D_DIM * D_DIM) / 4;

    cvt_bf16<<<2048, 256, 0, stream>>>(X, Xb, nX4);
    cvt_w3<<<2048, 256, 0, stream>>>(Wq, Wk, Wv, Wqkvb);

    // fused QKV: 32 x 24 = 768 blocks (3/CU)
    gemm_bt<3, 128, 128><<<dim3((M / 128) * (3072 / 128)), 256, 0, stream>>>(
        Xb, Wqkvb, bq, bk, bv, Qb, Kb, Vtb, M, 3072, D_DIM);

    // attn: 32 x 48 chunk-blocks, snake-balanced + staggered, pipelined
    dim3 agrid(BATCH * NH, 48);
    attn_fwd<<<agrid, 256, 0, stream>>>(Qb, Kb, Vtb, Ab, mlbuf, Pd);

    // merge split-tile partials (reads Pd + Ab partials, finalizes Ab)
    attn_merge<<<dim3(BATCH * NH, 16), 256, 0, stream>>>(mlbuf, Pd, Ab);

    cvt_bf16<<<2048, 256, 0, stream>>>(Wo, Wob, nW4);   // after merge (overlays mlbuf)

    // Wo gemm: 64x128 tiles -> 512 blocks (2/CU); overwrites all of d_out
    gemm_bt<2, 64, 128><<<dim3((M / 64) * (D_DIM / 128)), 256, 0, stream>>>(
        Ab, Wob, bo, bo, bo, out, out, out, M, D_DIM, D_DIM);
}

// Round 12
// 126.783 us; speedup vs baseline: 1.7011x; 1.0977x over previous
//
#include <hip/hip_runtime.h>
#include <hip/hip_bf16.h>
#include <cstdint>

typedef __attribute__((ext_vector_type(8))) short short8;
typedef __attribute__((ext_vector_type(4))) float f32x4;
typedef __attribute__((ext_vector_type(2))) unsigned int uint2v;
typedef unsigned short ushort_t;

#define S_LEN 2048
#define D_DIM 1024
#define NH 16
#define DK 64
#define BATCH 2
#define M_ROWS (BATCH * S_LEN)   // 4096
#define BK 32

__device__ inline ushort_t f2bf(float f) {
    union { float f; uint32_t u; } v; v.f = f;
    uint32_t r = v.u + 0x7fffu + ((v.u >> 16) & 1u);  // RNE
    return (ushort_t)(r >> 16);
}

__device__ __forceinline__ ushort_t bfc(float f) {
    __hip_bfloat16 h = __float2bfloat16(f);          // HW cvt path
    return __builtin_bit_cast(ushort_t, h);
}

__device__ __forceinline__ float bf2f(ushort_t u) {
    return __uint_as_float(((uint32_t)u) << 16);
}

// HW transcendentals (OCML exp2f/div are multi-instruction without fast-math)
__device__ __forceinline__ float fexp2(float x) {
#if __has_builtin(__builtin_amdgcn_exp2f)
    return __builtin_amdgcn_exp2f(x);
#else
    return exp2f(x);
#endif
}
__device__ __forceinline__ float frcp(float x) {
#if __has_builtin(__builtin_amdgcn_rcpf)
    return __builtin_amdgcn_rcpf(x);
#else
    return 1.0f / x;
#endif
}

__device__ __forceinline__ void glds16(const ushort_t* g, ushort_t* l) {
    __builtin_amdgcn_global_load_lds(
        (const __attribute__((address_space(1))) uint32_t*)g,
        (__attribute__((address_space(3))) uint32_t*)l,
        16, 0, 0);
}

#if __has_builtin(__builtin_amdgcn_permlane16_swap) && __has_builtin(__builtin_amdgcn_permlane32_swap)
#define HAS_PLSWAP 1
#else
#define HAS_PLSWAP 0
#endif

// cross-lane reduce over the 4 16-lane groups (lanes l, l^16, l^32, l^48)
__device__ __forceinline__ float red_max4(float x) {
#if HAS_PLSWAP
    uint2v a = __builtin_amdgcn_permlane16_swap(__float_as_uint(x), __float_as_uint(x), false, false);
    float y = fmaxf(__uint_as_float(a.x), __uint_as_float(a.y));
    uint2v b = __builtin_amdgcn_permlane32_swap(__float_as_uint(y), __float_as_uint(y), false, false);
    return fmaxf(__uint_as_float(b.x), __uint_as_float(b.y));
#else
    x = fmaxf(x, __shfl_xor(x, 16));
    return fmaxf(x, __shfl_xor(x, 32));
#endif
}
__device__ __forceinline__ float red_sum4(float x) {
#if HAS_PLSWAP
    uint2v a = __builtin_amdgcn_permlane16_swap(__float_as_uint(x), __float_as_uint(x), false, false);
    float y = __uint_as_float(a.x) + __uint_as_float(a.y);
    uint2v b = __builtin_amdgcn_permlane32_swap(__float_as_uint(y), __float_as_uint(y), false, false);
    return __uint_as_float(b.x) + __uint_as_float(b.y);
#else
    x += __shfl_xor(x, 16);
    return x + __shfl_xor(x, 32);
#endif
}

// T12 route: build PV A-frag words F[0..3] for k-slice ks from packed P words
// wp[n][h] (kv = 16n + 4*(lane>>4) + 2h + {0,1}, q = lane&15).
__device__ __forceinline__ void route_p(const uint32_t wp[4][2], int ks, int lane, uint32_t F[4]) {
#if HAS_PLSWAP
    uint32_t U0 = wp[2 * ks][0],     U1 = wp[2 * ks][1];
    uint32_t V0 = wp[2 * ks + 1][0], V1 = wp[2 * ks + 1][1];
    uint2v t, pa0, pa1, pb0, pb1;
    t = __builtin_amdgcn_permlane32_swap(U0, U0, false, false);
    pa0 = __builtin_amdgcn_permlane16_swap(U0, t.y, false, false);
    t = __builtin_amdgcn_permlane32_swap(U1, U1, false, false);
    pa1 = __builtin_amdgcn_permlane16_swap(U1, t.y, false, false);
    t = __builtin_amdgcn_permlane32_swap(V0, V0, false, false);
    pb0 = __builtin_amdgcn_permlane16_swap(t.x, V0, false, false);
    t = __builtin_amdgcn_permlane32_swap(V1, V1, false, false);
    pb1 = __builtin_amdgcn_permlane16_swap(t.x, V1, false, false);
    bool lo = lane < 32;
    F[0] = lo ? pa0.x : pb0.x;
    F[1] = lo ? pa1.x : pb1.x;
    F[2] = lo ? pa0.y : pb0.y;
    F[3] = lo ? pa1.y : pb1.y;
#else
    int q = lane & 15, g = lane >> 4;
#pragma unroll
    for (int m = 0; m < 4; m++) {
        int src = 16 * (2 * (g & 1) + (m >> 1)) + q;
        uint32_t xa = (uint32_t)__shfl((int)wp[2 * ks][m & 1], src);
        uint32_t xb = (uint32_t)__shfl((int)wp[2 * ks + 1][m & 1], src);
        F[m] = (g < 2) ? xa : xb;
    }
#endif
}

// ---------------- fp32 -> bf16 convert (vectorized) ----------------
__global__ void cvt_bf16(const float* __restrict__ in, ushort_t* __restrict__ out, int n4) {
    int i = blockIdx.x * blockDim.x + threadIdx.x;
    int stride = gridDim.x * blockDim.x;
    for (int idx = i; idx < n4; idx += stride) {
        float4 v = ((const float4*)in)[idx];
        ushort4 o;
        o.x = f2bf(v.x); o.y = f2bf(v.y); o.z = f2bf(v.z); o.w = f2bf(v.w);
        ((ushort4*)out)[idx] = o;
    }
}

// fused convert of Wq,Wk,Wv into one [3072,1024] bf16 buffer
__global__ void cvt_w3(const float* __restrict__ wq, const float* __restrict__ wk,
                       const float* __restrict__ wv, ushort_t* __restrict__ wqkv) {
    const int seg = (D_DIM * D_DIM) / 4;   // 2^18
    int i = blockIdx.x * blockDim.x + threadIdx.x;
    int stride = gridDim.x * blockDim.x;
    for (int idx = i; idx < 3 * seg; idx += stride) {
        int sel = idx >> 18;
        int id = idx & (seg - 1);
        const float* src = sel == 0 ? wq : (sel == 1 ? wk : wv);
        float4 v = ((const float4*)src)[id];
        ushort4 o;
        o.x = f2bf(v.x); o.y = f2bf(v.y); o.z = f2bf(v.z); o.w = f2bf(v.w);
        ((ushort4*)wqkv)[sel * seg + id] = o;
    }
}

// ---------------- GEMM: C = A[M,K] * Bw[N,K]^T + bias ----------------
// T1: bijective XCD remap (grid must be a multiple of 8 blocks).
template<int MODE, int BMt, int BNt>
__global__ __launch_bounds__(256) void gemm_bt(const ushort_t* __restrict__ A,
                                               const ushort_t* __restrict__ Bw,
                                               const float* __restrict__ b0,
                                               const float* __restrict__ b1,
                                               const float* __restrict__ b2,
                                               void* __restrict__ C0,
                                               void* __restrict__ C1,
                                               void* __restrict__ C2,
                                               int M, int N, int K) {
    constexpr int FM = BMt / 32, FN = BNt / 32;
    constexpr int ACH = BMt / 64, BCH = BNt / 64;
    __shared__ ushort_t As[BMt * BK];
    __shared__ ushort_t Bs[BNt * BK];
    int tid = threadIdx.x;
    int lane = tid & 63;
    int w = tid >> 6;
    int wr = w >> 1, wc = w & 1;
    // XCD-aware remap: consecutive logical tiles (same A panel) -> same XCD L2
    int nwg = gridDim.x;
    int bx = (blockIdx.x & 7) * (nwg >> 3) + (blockIdx.x >> 3);
    int ntile = N / BNt;
    int m0 = (bx / ntile) * BMt;
    int n0 = (bx % ntile) * BNt;
    int lr = lane & 15;
    int lk = (lane >> 4) * 8;
    int srow = lane >> 2;            // 0..15
    int scol = (lane & 3) * 8;

    f32x4 acc[FM][FN] = {};

    for (int kt = 0; kt < K; kt += BK) {
        __syncthreads();
#pragma unroll
        for (int c = 0; c < ACH; c++)
            glds16(&A[(size_t)(m0 + w * (BMt / 4) + c * 16 + srow) * K + kt + scol],
                   &As[(w * (BMt / 4) + c * 16) * BK]);
#pragma unroll
        for (int c = 0; c < BCH; c++)
            glds16(&Bw[(size_t)(n0 + w * (BNt / 4) + c * 16 + srow) * K + kt + scol],
                   &Bs[(w * (BNt / 4) + c * 16) * BK]);
        __syncthreads();

        short8 af[FM], bf[FN];
#pragma unroll
        for (int f = 0; f < FM; f++)
            af[f] = *(const short8*)&As[(wr * (BMt / 2) + f * 16 + lr) * BK + lk];
#pragma unroll
        for (int f = 0; f < FN; f++)
            bf[f] = *(const short8*)&Bs[(wc * (BNt / 2) + f * 16 + lr) * BK + lk];
#pragma unroll
        for (int i = 0; i < FM; i++)
#pragma unroll
            for (int j = 0; j < FN; j++)
                acc[i][j] = __builtin_amdgcn_mfma_f32_16x16x32_bf16(af[i], bf[j], acc[i][j], 0, 0, 0);
    }

    int r0 = (lane >> 4) * 4;
#pragma unroll
    for (int j = 0; j < FN; j++) {
        int ncol = n0 + wc * (BNt / 2) + j * 16 + lr;
        if (MODE == 2) {
            float bv = b0[ncol];
#pragma unroll
            for (int i = 0; i < FM; i++) {
                int mbase = m0 + wr * (BMt / 2) + i * 16 + r0;
#pragma unroll
                for (int r = 0; r < 4; r++)
                    ((float*)C0)[(size_t)(mbase + r) * N + ncol] = acc[i][j][r] + bv;
            }
        } else {
            int sel = n0 >> 10;                    // block-uniform
            const float* bp = sel == 0 ? b0 : (sel == 1 ? b1 : b2);
            int nc = ncol & 1023;
            float bv = bp[nc];
            int hh = nc >> 6, dk = nc & 63;
            ushort_t* Co = (ushort_t*)(sel == 0 ? C0 : (sel == 1 ? C1 : C2));
#pragma unroll
            for (int i = 0; i < FM; i++) {
                int mbase = m0 + wr * (BMt / 2) + i * 16 + r0;
                int bb = mbase >> 11, ss = mbase & 2047;
                if (sel == 2) {
                    ushort4 pk;
                    pk.x = f2bf(acc[i][j][0] + bv);
                    pk.y = f2bf(acc[i][j][1] + bv);
                    pk.z = f2bf(acc[i][j][2] + bv);
                    pk.w = f2bf(acc[i][j][3] + bv);
                    size_t idx = ((size_t)(bb * NH + hh) * DK + dk) * S_LEN + ss;
                    *(ushort4*)&Co[idx] = pk;
                } else {
#pragma unroll
                    for (int r = 0; r < 4; r++) {
                        size_t idx = ((size_t)(bb * NH + hh) * S_LEN + (ss + r)) * DK + dk;
                        Co[idx] = f2bf(acc[i][j][r] + bv);
                    }
                }
            }
        }
    }
}

// ---------------- Flash attention (causal, kv-split, full-residency) ----------------
// Grid (bh=32, y=40) = 1280 blocks = EXACTLY 5 blocks/CU at 32 KB LDS ->
// all blocks co-resident, no second dispatch wave (round-9's grid of 1536
// guaranteed a 256-block serial tail). Splits only j=24..31; j<=23 single.
// Residency classes r=y%8 each hold 5 chunks summing exactly 66 tile-units.
// Inner loop = round-9 verified machinery (unchanged).
#define CSC 0.1803368801f   // 0.125 * log2(e)

__device__ const unsigned char JTAB[40] = {
    23,22,21,20,19,18,17,16,
    31,31,30,28,29,26,27,15,
    24,25,30,28,29,27,26,14,
    24,11, 9,10, 8,25,12,13,
     0, 1, 2, 4, 6, 5, 7, 3};
__device__ const unsigned char KTAB[40] = {
     9, 9, 9, 9, 9, 9, 9, 9,
     0, 1, 0, 0, 0, 0, 1, 9,
     0, 0, 1, 1, 1, 0, 1, 9,
     1, 9, 9, 9, 9, 1, 9, 9,
     9, 9, 9, 9, 9, 9, 9, 9};

__global__ __launch_bounds__(256) void attn_fwd(const ushort_t* __restrict__ Q,
                                                const ushort_t* __restrict__ K,
                                                const ushort_t* __restrict__ Vt,
                                                ushort_t* __restrict__ Oa,
                                                float2* __restrict__ ml,
                                                float* __restrict__ Pd) {
    __shared__ ushort_t Ks[2][64 * 64];
    __shared__ ushort_t Vs[2][64 * 64];

    int tid = threadIdx.x;
    int lane = tid & 63;
    int w = tid >> 6;
    int bh = blockIdx.x;           // 0..31
    int yy = blockIdx.y;           // 0..39
    int j = JTAB[yy];
    int kk = KTAB[yy];             // 0/1 = split chunk, 9 = single
    int nt = j + 1;
    int half = (nt + 1) >> 1;
    int t0 = (kk == 1) ? half : 0;
    int t1 = (kk == 0) ? half : nt;
    int cnt = t1 - t0;
    int off = yy % cnt;            // per-block stagger (same-CU mates differ)
    size_t base = (size_t)bh * S_LEN * DK;
    int q0 = j * 64;

    int lr = lane & 15;
    int lk = (lane >> 4) * 8;
    int g16 = (lane >> 4) * 16;    // byte col of fragment k-slice
    int r0 = (lane >> 4) * 4;
    int wq = w * 16 + lr;          // this lane's q row (within tile)

    // XOR swizzle: ushort index for (row, byte-col) in a [64][128B] tile
    auto swz = [](int row, int cb) { return (row * 128 + (cb ^ ((row & 7) << 4))) >> 1; };

    // Q fragment (16 rows per wave)
    short8 qf0 = *(const short8*)&Q[base + (size_t)(q0 + wq) * DK + lk];
    short8 qf1 = *(const short8*)&Q[base + (size_t)(q0 + wq) * DK + 32 + lk];

    f32x4 o[4] = {};
    float mrowL = -1e30f, lrow = 0.f;

    int sr = tid >> 3;            // 0..31
    int scb = (tid & 7) * 16;     // byte col
    int sce = (tid & 7) * 8;      // element col

    // prologue: stage first (staggered) tile into buf 0 (swizzled)
    {
        int tf = t0 + off;
        *(uint4*)&Ks[0][swz(sr, scb)]      = *(const uint4*)&K [base + (size_t)(tf * 64 + sr) * DK + sce];
        *(uint4*)&Ks[0][swz(sr + 32, scb)] = *(const uint4*)&K [base + (size_t)(tf * 64 + sr + 32) * DK + sce];
        *(uint4*)&Vs[0][swz(sr, scb)]      = *(const uint4*)&Vt[base + (size_t)sr * S_LEN + tf * 64 + sce];
        *(uint4*)&Vs[0][swz(sr + 32, scb)] = *(const uint4*)&Vt[base + (size_t)(sr + 32) * S_LEN + tf * 64 + sce];
    }
    __syncthreads();

    int cur = 0;
    for (int s = 0; s < cnt; ++s) {
        int to = s + off; if (to >= cnt) to -= cnt;
        int t = t0 + to;
        bool last = (s == cnt - 1);
        bool diag = (t == j);
        uint4 kr0, kr1, vr0, vr1;
        if (!last) {
            int tno = s + 1 + off; if (tno >= cnt) tno -= cnt;
            int tn = t0 + tno;
            kr0 = *(const uint4*)&K [base + (size_t)(tn * 64 + sr) * DK + sce];
            kr1 = *(const uint4*)&K [base + (size_t)(tn * 64 + sr + 32) * DK + sce];
            vr0 = *(const uint4*)&Vt[base + (size_t)sr * S_LEN + tn * 64 + sce];
            vr1 = *(const uint4*)&Vt[base + (size_t)(sr + 32) * S_LEN + tn * 64 + sce];
        }

        // swapped QK^T: st rows = kv (regs), cols = q (lanes)
        f32x4 st[4] = {};
        __builtin_amdgcn_s_setprio(1);
#pragma unroll
        for (int n = 0; n < 4; n++) {
            if (!diag || n <= w) {   // skip fully-masked kv frags on diagonal
                short8 kf0 = *(const short8*)&Ks[cur][swz(n * 16 + lr, g16)];
                short8 kf1 = *(const short8*)&Ks[cur][swz(n * 16 + lr, 64 + g16)];
                st[n] = __builtin_amdgcn_mfma_f32_16x16x32_bf16(kf0, qf0, st[n], 0, 0, 0);
                st[n] = __builtin_amdgcn_mfma_f32_16x16x32_bf16(kf1, qf1, st[n], 0, 0, 0);
            }
        }
        __builtin_amdgcn_s_setprio(0);

        if (diag) {   // causal mask within diagonal tile
#pragma unroll
            for (int n = 0; n < 4; n++)
#pragma unroll
                for (int i = 0; i < 4; i++)
                    if (16 * n + r0 + i > wq) st[n][i] = -1e30f;
        }

        // per-lane softmax (q = lr), reduce across 4 lane-groups
        float m0 = fmaxf(fmaxf(fmaxf(st[0][0], st[0][1]), st[0][2]), st[0][3]);
        float m1 = fmaxf(fmaxf(fmaxf(st[1][0], st[1][1]), st[1][2]), st[1][3]);
        float m2 = fmaxf(fmaxf(fmaxf(st[2][0], st[2][1]), st[2][2]), st[2][3]);
        float m3 = fmaxf(fmaxf(fmaxf(st[3][0], st[3][1]), st[3][2]), st[3][3]);
        float mx = fmaxf(fmaxf(fmaxf(m0, m1), m2), m3);
        float mxL = red_max4(mx) * CSC;

        bool skip = __all(mxL <= mrowL + 8.0f);   // T13 defer-max
        float corr = 1.0f;
        float mnewL = mrowL;
        if (!skip) {
            mnewL = fmaxf(mrowL, mxL);
            corr = fexp2(mrowL - mnewL);
            mrowL = mnewL;
        }

        float psum = 0.f;
        uint32_t wp[4][2];
#pragma unroll
        for (int n = 0; n < 4; n++) {
#pragma unroll
            for (int i = 0; i < 4; i++) {
                float p = fexp2(fmaf(st[n][i], CSC, -mnewL));
                st[n][i] = p;
                psum += p;
            }
            wp[n][0] = (uint32_t)bfc(st[n][0]) | ((uint32_t)bfc(st[n][1]) << 16);
            wp[n][1] = (uint32_t)bfc(st[n][2]) | ((uint32_t)bfc(st[n][3]) << 16);
        }
        psum = red_sum4(psum);

        if (skip) {
            lrow += psum;
        } else {
            lrow = lrow * corr + psum;
            float cb[4];
#pragma unroll
            for (int i = 0; i < 4; i++) cb[i] = __shfl(corr, r0 + i);
#pragma unroll
            for (int d = 0; d < 4; d++)
#pragma unroll
                for (int i = 0; i < 4; i++) o[d][i] *= cb[i];
        }

        // PV: O += P V, P frags routed in-register
#pragma unroll
        for (int ks = 0; ks < 2; ks++) {
            if (diag && 32 * ks > w * 16 + 15) continue;  // slice fully masked
            uint32_t F[4];
            route_p(wp, ks, lane, F);
            union { uint32_t u[4]; short8 s; } pu;
            pu.u[0] = F[0]; pu.u[1] = F[1]; pu.u[2] = F[2]; pu.u[3] = F[3];
            short8 pf = pu.s;
            __builtin_amdgcn_s_setprio(1);
#pragma unroll
            for (int d = 0; d < 4; d++) {
                short8 vf = *(const short8*)&Vs[cur][swz(d * 16 + lr, ks * 64 + g16)];
                o[d] = __builtin_amdgcn_mfma_f32_16x16x32_bf16(pf, vf, o[d], 0, 0, 0);
            }
            __builtin_amdgcn_s_setprio(0);
        }

        if (!last) {
            *(uint4*)&Ks[cur ^ 1][swz(sr, scb)]      = kr0;
            *(uint4*)&Ks[cur ^ 1][swz(sr + 32, scb)] = kr1;
            *(uint4*)&Vs[cur ^ 1][swz(sr, scb)]      = vr0;
            *(uint4*)&Vs[cur ^ 1][swz(sr + 32, scb)] = vr1;
        }
        __syncthreads();
        cur ^= 1;
    }

    // epilogue
    int b = bh >> 4, h = bh & 15;
    if (kk == 9) {
        // single chunk: normalize and write final bf16
        float lb[4];
#pragma unroll
        for (int i = 0; i < 4; i++) lb[i] = frcp(__shfl(lrow, r0 + i));
#pragma unroll
        for (int d = 0; d < 4; d++)
#pragma unroll
            for (int i = 0; i < 4; i++) {
                int qq = q0 + w * 16 + r0 + i;
                int dk = d * 16 + lr;
                size_t idx = ((size_t)(b * S_LEN + qq)) * D_DIM + h * DK + dk;
                Oa[idx] = bfc(o[d][i] * lb[i]);
            }
    } else {
        int jj = j - 24;               // split j's are 24..31
        if (kk == 0) {
            // chunk0 partial: unnormalized bf16 into the final O slot
#pragma unroll
            for (int d = 0; d < 4; d++)
#pragma unroll
                for (int i = 0; i < 4; i++) {
                    int qq = q0 + w * 16 + r0 + i;
                    int dk = d * 16 + lr;
                    size_t idx = ((size_t)(b * S_LEN + qq)) * D_DIM + h * DK + dk;
                    Oa[idx] = bfc(o[d][i]);
                }
        } else {
            // chunk1 partial: f32 into Pd scratch (d_out)
#pragma unroll
            for (int d = 0; d < 4; d++)
#pragma unroll
                for (int i = 0; i < 4; i++) {
                    int rloc = w * 16 + r0 + i;
                    Pd[((size_t)(bh * 8 + jj) * 64 + rloc) * 64 + d * 16 + lr] = o[d][i];
                }
        }
        if (lane < 16) {
            int row = w * 16 + lane;   // lanes 0..15 hold rows (q=lr) stats
            ml[(size_t)kk * 16384 + (bh * 8 + jj) * 64 + row] = make_float2(mrowL, lrow);
        }
    }
}

// ---------------- merge of split-tile partials (j = 24..31) ----------------
__global__ __launch_bounds__(256) void attn_merge(const float2* __restrict__ ml,
                                                  const float* __restrict__ Pd,
                                                  ushort_t* __restrict__ Oa) {
    int bh = blockIdx.x;           // 0..31
    int jj = blockIdx.y;           // 0..7 -> j = jj+24
    int tid = threadIdx.x;
    int r = tid >> 2;              // row 0..63
    int q = (tid & 3) * 16;        // dk start
    int b = bh >> 4, h = bh & 15;
    int row = (jj + 24) * 64 + r;
    float2 a = ml[(bh * 8 + jj) * 64 + r];
    float2 c = ml[16384 + (bh * 8 + jj) * 64 + r];
    float M = fmaxf(a.x, c.x);
    float w0 = fexp2(a.x - M), w1 = fexp2(c.x - M);
    float rc = frcp(a.y * w0 + c.y * w1);
    size_t ob = ((size_t)(b * S_LEN + row)) * D_DIM + h * DK + q;
    const float* p1 = &Pd[((size_t)(bh * 8 + jj) * 64 + r) * 64 + q];
#pragma unroll
    for (int i = 0; i < 4; i++) {
        ushort4 o0 = *(const ushort4*)&Oa[ob + i * 4];
        float4 o1 = *(const float4*)&p1[i * 4];
        ushort4 res;
        res.x = bfc((bf2f(o0.x) * w0 + o1.x * w1) * rc);
        res.y = bfc((bf2f(o0.y) * w0 + o1.y * w1) * rc);
        res.z = bfc((bf2f(o0.z) * w0 + o1.z * w1) * rc);
        res.w = bfc((bf2f(o0.w) * w0 + o1.w * w1) * rc);
        *(ushort4*)&Oa[ob + i * 4] = res;
    }
}

// ---------------- launch ----------------
extern "C" void kernel_launch(void* const* d_in, const int* in_sizes, int n_in,
                              void* d_out, int out_size, void* d_ws, size_t ws_size,
                              hipStream_t stream) {
    const float* X  = (const float*)d_in[0];
    const float* Wq = (const float*)d_in[1];
    const float* bq = (const float*)d_in[2];
    const float* Wk = (const float*)d_in[3];
    const float* bk = (const float*)d_in[4];
    const float* Wv = (const float*)d_in[5];
    const float* bv = (const float*)d_in[6];
    const float* Wo = (const float*)d_in[7];
    const float* bo = (const float*)d_in[8];
    float* out = (float*)d_out;

    char* ws = (char*)d_ws;
    ushort_t* Xb    = (ushort_t*)ws;                        // 8 MiB [M,D] bf16 (later: attn out)
    ushort_t* Wqkvb = (ushort_t*)(ws + (8u  << 20));        // 6 MiB; dead after QKV gemm
    float2*   mlbuf = (float2*)(ws + (8u  << 20));          // 256 KiB (over dead Wqkvb)
    ushort_t* Qb    = (ushort_t*)(ws + (14u << 20));        // 8 MiB [b,h,s,dk]
    ushort_t* Kb    = (ushort_t*)(ws + (22u << 20));        // 8 MiB [b,h,s,dk]
    ushort_t* Vtb   = (ushort_t*)(ws + (30u << 20));        // 8 MiB [b,h,dk,s]
    ushort_t* Wob   = Wqkvb;                                // reuse after merge
    ushort_t* Ab    = Xb;                                   // attn out reuses X slot
    float*    Pd    = out;                                  // chunk1 partials scratch (dead until Wo gemm)

    const int M = M_ROWS;
    int nX4 = (M * D_DIM) / 4;
    int nW4 = (D_DIM * D_DIM) / 4;

    cvt_bf16<<<2048, 256, 0, stream>>>(X, Xb, nX4);
    cvt_w3<<<2048, 256, 0, stream>>>(Wq, Wk, Wv, Wqkvb);

    // fused QKV: 32 x 24 = 768 blocks (3/CU)
    gemm_bt<3, 128, 128><<<dim3((M / 128) * (3072 / 128)), 256, 0, stream>>>(
        Xb, Wqkvb, bq, bk, bv, Qb, Kb, Vtb, M, 3072, D_DIM);

    // attn: 32 x 40 = 1280 chunk-blocks = exactly 5/CU, all co-resident
    dim3 agrid(BATCH * NH, 40);
    attn_fwd<<<agrid, 256, 0, stream>>>(Qb, Kb, Vtb, Ab, mlbuf, Pd);

    // merge split-tile partials (j=24..31)
    attn_merge<<<dim3(BATCH * NH, 8), 256, 0, stream>>>(mlbuf, Pd, Ab);

    cvt_bf16<<<2048, 256, 0, stream>>>(Wo, Wob, nW4);   // after merge (overlays mlbuf)

    // Wo gemm: 64x128 tiles -> 512 blocks (2/CU); overwrites all of d_out
    gemm_bt<2, 64, 128><<<dim3((M / 64) * (D_DIM / 128)), 256, 0, stream>>>(
        Ab, Wob, bo, bo, bo, out, out, out, M, D_DIM, D_DIM);
}

// Round 13
// 119.069 us; speedup vs baseline: 1.8113x; 1.0648x over previous
//
#include <hip/hip_runtime.h>
#include <hip/hip_bf16.h>
#include <cstdint>

typedef __attribute__((ext_vector_type(8))) short short8;
typedef __attribute__((ext_vector_type(4))) float f32x4;
typedef __attribute__((ext_vector_type(2))) unsigned int uint2v;
typedef unsigned short ushort_t;

#define S_LEN 2048
#define D_DIM 1024
#define NH 16
#define DK 64
#define BATCH 2
#define M_ROWS (BATCH * S_LEN)   // 4096
#define BK 32

__device__ inline ushort_t f2bf(float f) {
    union { float f; uint32_t u; } v; v.f = f;
    uint32_t r = v.u + 0x7fffu + ((v.u >> 16) & 1u);  // RNE
    return (ushort_t)(r >> 16);
}

__device__ __forceinline__ ushort_t bfc(float f) {
    __hip_bfloat16 h = __float2bfloat16(f);          // HW cvt path
    return __builtin_bit_cast(ushort_t, h);
}

__device__ __forceinline__ float bf2f(ushort_t u) {
    return __uint_as_float(((uint32_t)u) << 16);
}

// HW transcendentals (OCML exp2f/div are multi-instruction without fast-math)
__device__ __forceinline__ float fexp2(float x) {
#if __has_builtin(__builtin_amdgcn_exp2f)
    return __builtin_amdgcn_exp2f(x);
#else
    return exp2f(x);
#endif
}
__device__ __forceinline__ float frcp(float x) {
#if __has_builtin(__builtin_amdgcn_rcpf)
    return __builtin_amdgcn_rcpf(x);
#else
    return 1.0f / x;
#endif
}

__device__ __forceinline__ void glds16(const ushort_t* g, ushort_t* l) {
    __builtin_amdgcn_global_load_lds(
        (const __attribute__((address_space(1))) uint32_t*)g,
        (__attribute__((address_space(3))) uint32_t*)l,
        16, 0, 0);
}

#if __has_builtin(__builtin_amdgcn_permlane16_swap) && __has_builtin(__builtin_amdgcn_permlane32_swap)
#define HAS_PLSWAP 1
#else
#define HAS_PLSWAP 0
#endif

// cross-lane reduce over the 4 16-lane groups (lanes l, l^16, l^32, l^48)
__device__ __forceinline__ float red_max4(float x) {
#if HAS_PLSWAP
    uint2v a = __builtin_amdgcn_permlane16_swap(__float_as_uint(x), __float_as_uint(x), false, false);
    float y = fmaxf(__uint_as_float(a.x), __uint_as_float(a.y));
    uint2v b = __builtin_amdgcn_permlane32_swap(__float_as_uint(y), __float_as_uint(y), false, false);
    return fmaxf(__uint_as_float(b.x), __uint_as_float(b.y));
#else
    x = fmaxf(x, __shfl_xor(x, 16));
    return fmaxf(x, __shfl_xor(x, 32));
#endif
}
__device__ __forceinline__ float red_sum4(float x) {
#if HAS_PLSWAP
    uint2v a = __builtin_amdgcn_permlane16_swap(__float_as_uint(x), __float_as_uint(x), false, false);
    float y = __uint_as_float(a.x) + __uint_as_float(a.y);
    uint2v b = __builtin_amdgcn_permlane32_swap(__float_as_uint(y), __float_as_uint(y), false, false);
    return __uint_as_float(b.x) + __uint_as_float(b.y);
#else
    x += __shfl_xor(x, 16);
    return x + __shfl_xor(x, 32);
#endif
}

// T12 route: build PV A-frag words F[0..3] for k-slice ks from packed P words
// wp[n][h] (kv = 16n + 4*(lane>>4) + 2h + {0,1}, q = lane&15).
__device__ __forceinline__ void route_p(const uint32_t wp[4][2], int ks, int lane, uint32_t F[4]) {
#if HAS_PLSWAP
    uint32_t U0 = wp[2 * ks][0],     U1 = wp[2 * ks][1];
    uint32_t V0 = wp[2 * ks + 1][0], V1 = wp[2 * ks + 1][1];
    uint2v t, pa0, pa1, pb0, pb1;
    t = __builtin_amdgcn_permlane32_swap(U0, U0, false, false);
    pa0 = __builtin_amdgcn_permlane16_swap(U0, t.y, false, false);
    t = __builtin_amdgcn_permlane32_swap(U1, U1, false, false);
    pa1 = __builtin_amdgcn_permlane16_swap(U1, t.y, false, false);
    t = __builtin_amdgcn_permlane32_swap(V0, V0, false, false);
    pb0 = __builtin_amdgcn_permlane16_swap(t.x, V0, false, false);
    t = __builtin_amdgcn_permlane32_swap(V1, V1, false, false);
    pb1 = __builtin_amdgcn_permlane16_swap(t.x, V1, false, false);
    bool lo = lane < 32;
    F[0] = lo ? pa0.x : pb0.x;
    F[1] = lo ? pa1.x : pb1.x;
    F[2] = lo ? pa0.y : pb0.y;
    F[3] = lo ? pa1.y : pb1.y;
#else
    int q = lane & 15, g = lane >> 4;
#pragma unroll
    for (int m = 0; m < 4; m++) {
        int src = 16 * (2 * (g & 1) + (m >> 1)) + q;
        uint32_t xa = (uint32_t)__shfl((int)wp[2 * ks][m & 1], src);
        uint32_t xb = (uint32_t)__shfl((int)wp[2 * ks + 1][m & 1], src);
        F[m] = (g < 2) ? xa : xb;
    }
#endif
}

// ---------------- fp32 -> bf16 convert (vectorized) ----------------
__global__ void cvt_bf16(const float* __restrict__ in, ushort_t* __restrict__ out, int n4) {
    int i = blockIdx.x * blockDim.x + threadIdx.x;
    int stride = gridDim.x * blockDim.x;
    for (int idx = i; idx < n4; idx += stride) {
        float4 v = ((const float4*)in)[idx];
        ushort4 o;
        o.x = f2bf(v.x); o.y = f2bf(v.y); o.z = f2bf(v.z); o.w = f2bf(v.w);
        ((ushort4*)out)[idx] = o;
    }
}

// fused convert of Wq,Wk,Wv into one [3072,1024] bf16 buffer
__global__ void cvt_w3(const float* __restrict__ wq, const float* __restrict__ wk,
                       const float* __restrict__ wv, ushort_t* __restrict__ wqkv) {
    const int seg = (D_DIM * D_DIM) / 4;   // 2^18
    int i = blockIdx.x * blockDim.x + threadIdx.x;
    int stride = gridDim.x * blockDim.x;
    for (int idx = i; idx < 3 * seg; idx += stride) {
        int sel = idx >> 18;
        int id = idx & (seg - 1);
        const float* src = sel == 0 ? wq : (sel == 1 ? wk : wv);
        float4 v = ((const float4*)src)[id];
        ushort4 o;
        o.x = f2bf(v.x); o.y = f2bf(v.y); o.z = f2bf(v.z); o.w = f2bf(v.w);
        ((ushort4*)wqkv)[sel * seg + id] = o;
    }
}

// ---------------- GEMM: C = A[M,K] * Bw[N,K]^T + bias ----------------
// T1 XCD remap + single-barrier double-buffered staging (T3 minimal 2-phase):
// iteration kt stages buf^1 (glds, in flight during MFMA), reads buf, one
// barrier at end (compiler drains vmcnt+lgkmcnt before s_barrier).
template<int MODE, int BMt, int BNt>
__global__ __launch_bounds__(256, 3) void gemm_bt(const ushort_t* __restrict__ A,
                                                  const ushort_t* __restrict__ Bw,
                                                  const float* __restrict__ b0,
                                                  const float* __restrict__ b1,
                                                  const float* __restrict__ b2,
                                                  void* __restrict__ C0,
                                                  void* __restrict__ C1,
                                                  void* __restrict__ C2,
                                                  int M, int N, int K) {
    constexpr int FM = BMt / 32, FN = BNt / 32;
    constexpr int ACH = BMt / 64, BCH = BNt / 64;
    __shared__ ushort_t As[2][BMt * BK];
    __shared__ ushort_t Bs[2][BNt * BK];
    int tid = threadIdx.x;
    int lane = tid & 63;
    int w = tid >> 6;
    int wr = w >> 1, wc = w & 1;
    // XCD-aware remap: consecutive logical tiles (same A panel) -> same XCD L2
    int nwg = gridDim.x;
    int bx = (blockIdx.x & 7) * (nwg >> 3) + (blockIdx.x >> 3);
    int ntile = N / BNt;
    int m0 = (bx / ntile) * BMt;
    int n0 = (bx % ntile) * BNt;
    int lr = lane & 15;
    int lk = (lane >> 4) * 8;
    int srow = lane >> 2;            // 0..15
    int scol = (lane & 3) * 8;

    auto stage = [&](int b, int kt) {
#pragma unroll
        for (int c = 0; c < ACH; c++)
            glds16(&A[(size_t)(m0 + w * (BMt / 4) + c * 16 + srow) * K + kt + scol],
                   &As[b][(w * (BMt / 4) + c * 16) * BK]);
#pragma unroll
        for (int c = 0; c < BCH; c++)
            glds16(&Bw[(size_t)(n0 + w * (BNt / 4) + c * 16 + srow) * K + kt + scol],
                   &Bs[b][(w * (BNt / 4) + c * 16) * BK]);
    };

    f32x4 acc[FM][FN] = {};

    stage(0, 0);
    __syncthreads();                 // drain prologue glds
    int cur = 0;
    for (int kt = 0; kt < K; kt += BK) {
        if (kt + BK < K) stage(cur ^ 1, kt + BK);   // next tile in flight

        short8 af[FM], bf[FN];
#pragma unroll
        for (int f = 0; f < FM; f++)
            af[f] = *(const short8*)&As[cur][(wr * (BMt / 2) + f * 16 + lr) * BK + lk];
#pragma unroll
        for (int f = 0; f < FN; f++)
            bf[f] = *(const short8*)&Bs[cur][(wc * (BNt / 2) + f * 16 + lr) * BK + lk];
#pragma unroll
        for (int i = 0; i < FM; i++)
#pragma unroll
            for (int j = 0; j < FN; j++)
                acc[i][j] = __builtin_amdgcn_mfma_f32_16x16x32_bf16(af[i], bf[j], acc[i][j], 0, 0, 0);

        __syncthreads();             // drains this iter's glds + ds_reads
        cur ^= 1;
    }

    int r0 = (lane >> 4) * 4;
#pragma unroll
    for (int j = 0; j < FN; j++) {
        int ncol = n0 + wc * (BNt / 2) + j * 16 + lr;
        if (MODE == 2) {
            float bv = b0[ncol];
#pragma unroll
            for (int i = 0; i < FM; i++) {
                int mbase = m0 + wr * (BMt / 2) + i * 16 + r0;
#pragma unroll
                for (int r = 0; r < 4; r++)
                    ((float*)C0)[(size_t)(mbase + r) * N + ncol] = acc[i][j][r] + bv;
            }
        } else {
            int sel = n0 >> 10;                    // block-uniform
            const float* bp = sel == 0 ? b0 : (sel == 1 ? b1 : b2);
            int nc = ncol & 1023;
            float bv = bp[nc];
            int hh = nc >> 6, dk = nc & 63;
            ushort_t* Co = (ushort_t*)(sel == 0 ? C0 : (sel == 1 ? C1 : C2));
#pragma unroll
            for (int i = 0; i < FM; i++) {
                int mbase = m0 + wr * (BMt / 2) + i * 16 + r0;
                int bb = mbase >> 11, ss = mbase & 2047;
                if (sel == 2) {
                    ushort4 pk;
                    pk.x = f2bf(acc[i][j][0] + bv);
                    pk.y = f2bf(acc[i][j][1] + bv);
                    pk.z = f2bf(acc[i][j][2] + bv);
                    pk.w = f2bf(acc[i][j][3] + bv);
                    size_t idx = ((size_t)(bb * NH + hh) * DK + dk) * S_LEN + ss;
                    *(ushort4*)&Co[idx] = pk;
                } else {
#pragma unroll
                    for (int r = 0; r < 4; r++) {
                        size_t idx = ((size_t)(bb * NH + hh) * S_LEN + (ss + r)) * DK + dk;
                        Co[idx] = f2bf(acc[i][j][r] + bv);
                    }
                }
            }
        }
    }
}

// ---------------- Flash attention (causal, kv-split, full-residency) ----------------
// Round-12 structure (1280 blocks = 5/CU, snake-balanced, staggered).
// NEW: __launch_bounds__(256,5) matches the real LDS-capped occupancy so the
// compiler may use ~102 VGPR (hoist instead of recompute); staging addresses
// strength-reduced to incremental pointer advances with conditional wrap.
#define CSC 0.1803368801f   // 0.125 * log2(e)

__device__ const unsigned char JTAB[40] = {
    23,22,21,20,19,18,17,16,
    31,31,30,28,29,26,27,15,
    24,25,30,28,29,27,26,14,
    24,11, 9,10, 8,25,12,13,
     0, 1, 2, 4, 6, 5, 7, 3};
__device__ const unsigned char KTAB[40] = {
     9, 9, 9, 9, 9, 9, 9, 9,
     0, 1, 0, 0, 0, 0, 1, 9,
     0, 0, 1, 1, 1, 0, 1, 9,
     1, 9, 9, 9, 9, 1, 9, 9,
     9, 9, 9, 9, 9, 9, 9, 9};

__global__ __launch_bounds__(256, 5) void attn_fwd(const ushort_t* __restrict__ Q,
                                                   const ushort_t* __restrict__ K,
                                                   const ushort_t* __restrict__ Vt,
                                                   ushort_t* __restrict__ Oa,
                                                   float2* __restrict__ ml,
                                                   float* __restrict__ Pd) {
    __shared__ ushort_t Ks[2][64 * 64];
    __shared__ ushort_t Vs[2][64 * 64];

    int tid = threadIdx.x;
    int lane = tid & 63;
    int w = tid >> 6;
    int bh = blockIdx.x;           // 0..31
    int yy = blockIdx.y;           // 0..39
    int j = JTAB[yy];
    int kk = KTAB[yy];             // 0/1 = split chunk, 9 = single
    int nt = j + 1;
    int half = (nt + 1) >> 1;
    int t0 = (kk == 1) ? half : 0;
    int t1 = (kk == 0) ? half : nt;
    int cnt = t1 - t0;
    int off = yy % cnt;            // per-block stagger (same-CU mates differ)
    size_t base = (size_t)bh * S_LEN * DK;
    int q0 = j * 64;

    int lr = lane & 15;
    int lk = (lane >> 4) * 8;
    int g16 = (lane >> 4) * 16;    // byte col of fragment k-slice
    int r0 = (lane >> 4) * 4;
    int wq = w * 16 + lr;          // this lane's q row (within tile)

    // XOR swizzle: ushort index for (row, byte-col) in a [64][128B] tile
    auto swz = [](int row, int cb) { return (row * 128 + (cb ^ ((row & 7) << 4))) >> 1; };

    // Q fragment (16 rows per wave)
    short8 qf0 = *(const short8*)&Q[base + (size_t)(q0 + wq) * DK + lk];
    short8 qf1 = *(const short8*)&Q[base + (size_t)(q0 + wq) * DK + 32 + lk];

    f32x4 o[4] = {};
    float mrowL = -1e30f, lrow = 0.f;

    int sr = tid >> 3;            // 0..31
    int scb = (tid & 7) * 16;     // byte col
    int sce = (tid & 7) * 8;      // element col

    // staging source bases (strength-reduced; advance incrementally)
    const ushort_t* kBase = K  + base + (size_t)sr * DK + sce;
    const ushort_t* vBase = Vt + base + (size_t)sr * S_LEN + sce;

    // prologue: stage first (staggered) tile into buf 0 (swizzled)
    int tf = t0 + off;
    {
        const ushort_t* kp = kBase + (size_t)tf * (64 * DK);
        const ushort_t* vp = vBase + (size_t)tf * 64;
        *(uint4*)&Ks[0][swz(sr, scb)]      = *(const uint4*)kp;
        *(uint4*)&Ks[0][swz(sr + 32, scb)] = *(const uint4*)(kp + 32 * DK);
        *(uint4*)&Vs[0][swz(sr, scb)]      = *(const uint4*)vp;
        *(uint4*)&Vs[0][swz(sr + 32, scb)] = *(const uint4*)(vp + 32 * S_LEN);
    }
    __syncthreads();

    int t = tf;                                    // current tile
    int tpre = (tf == t1 - 1) ? t0 : tf + 1;       // prefetch target
    const ushort_t* kPre = kBase + (size_t)tpre * (64 * DK);
    const ushort_t* vPre = vBase + (size_t)tpre * 64;

    int cur = 0;
    for (int s = 0; s < cnt; ++s) {
        bool last = (s == cnt - 1);
        bool diag = (t == j);
        uint4 kr0, kr1, vr0, vr1;
        if (!last) {
            kr0 = *(const uint4*)kPre;
            kr1 = *(const uint4*)(kPre + 32 * DK);
            vr0 = *(const uint4*)vPre;
            vr1 = *(const uint4*)(vPre + 32 * S_LEN);
        }

        // swapped QK^T: st rows = kv (regs), cols = q (lanes)
        f32x4 st[4] = {};
        __builtin_amdgcn_s_setprio(1);
#pragma unroll
        for (int n = 0; n < 4; n++) {
            if (!diag || n <= w) {   // skip fully-masked kv frags on diagonal
                short8 kf0 = *(const short8*)&Ks[cur][swz(n * 16 + lr, g16)];
                short8 kf1 = *(const short8*)&Ks[cur][swz(n * 16 + lr, 64 + g16)];
                st[n] = __builtin_amdgcn_mfma_f32_16x16x32_bf16(kf0, qf0, st[n], 0, 0, 0);
                st[n] = __builtin_amdgcn_mfma_f32_16x16x32_bf16(kf1, qf1, st[n], 0, 0, 0);
            }
        }
        __builtin_amdgcn_s_setprio(0);

        if (diag) {   // causal mask within diagonal tile
#pragma unroll
            for (int n = 0; n < 4; n++)
#pragma unroll
                for (int i = 0; i < 4; i++)
                    if (16 * n + r0 + i > wq) st[n][i] = -1e30f;
        }

        // per-lane softmax (q = lr), reduce across 4 lane-groups
        float m0 = fmaxf(fmaxf(fmaxf(st[0][0], st[0][1]), st[0][2]), st[0][3]);
        float m1 = fmaxf(fmaxf(fmaxf(st[1][0], st[1][1]), st[1][2]), st[1][3]);
        float m2 = fmaxf(fmaxf(fmaxf(st[2][0], st[2][1]), st[2][2]), st[2][3]);
        float m3 = fmaxf(fmaxf(fmaxf(st[3][0], st[3][1]), st[3][2]), st[3][3]);
        float mx = fmaxf(fmaxf(fmaxf(m0, m1), m2), m3);
        float mxL = red_max4(mx) * CSC;

        bool skip = __all(mxL <= mrowL + 8.0f);   // T13 defer-max
        float corr = 1.0f;
        float mnewL = mrowL;
        if (!skip) {
            mnewL = fmaxf(mrowL, mxL);
            corr = fexp2(mrowL - mnewL);
            mrowL = mnewL;
        }

        float psum = 0.f;
        uint32_t wp[4][2];
#pragma unroll
        for (int n = 0; n < 4; n++) {
#pragma unroll
            for (int i = 0; i < 4; i++) {
                float p = fexp2(fmaf(st[n][i], CSC, -mnewL));
                st[n][i] = p;
                psum += p;
            }
            wp[n][0] = (uint32_t)bfc(st[n][0]) | ((uint32_t)bfc(st[n][1]) << 16);
            wp[n][1] = (uint32_t)bfc(st[n][2]) | ((uint32_t)bfc(st[n][3]) << 16);
        }
        psum = red_sum4(psum);

        if (skip) {
            lrow += psum;
        } else {
            lrow = lrow * corr + psum;
            float cb[4];
#pragma unroll
            for (int i = 0; i < 4; i++) cb[i] = __shfl(corr, r0 + i);
#pragma unroll
            for (int d = 0; d < 4; d++)
#pragma unroll
                for (int i = 0; i < 4; i++) o[d][i] *= cb[i];
        }

        // PV: O += P V, P frags routed in-register
#pragma unroll
        for (int ks = 0; ks < 2; ks++) {
            if (diag && 32 * ks > w * 16 + 15) continue;  // slice fully masked
            uint32_t F[4];
            route_p(wp, ks, lane, F);
            union { uint32_t u[4]; short8 s; } pu;
            pu.u[0] = F[0]; pu.u[1] = F[1]; pu.u[2] = F[2]; pu.u[3] = F[3];
            short8 pf = pu.s;
            __builtin_amdgcn_s_setprio(1);
#pragma unroll
            for (int d = 0; d < 4; d++) {
                short8 vf = *(const short8*)&Vs[cur][swz(d * 16 + lr, ks * 64 + g16)];
                o[d] = __builtin_amdgcn_mfma_f32_16x16x32_bf16(pf, vf, o[d], 0, 0, 0);
            }
            __builtin_amdgcn_s_setprio(0);
        }

        if (!last) {
            *(uint4*)&Ks[cur ^ 1][swz(sr, scb)]      = kr0;
            *(uint4*)&Ks[cur ^ 1][swz(sr + 32, scb)] = kr1;
            *(uint4*)&Vs[cur ^ 1][swz(sr, scb)]      = vr0;
            *(uint4*)&Vs[cur ^ 1][swz(sr + 32, scb)] = vr1;
        }
        __syncthreads();
        cur ^= 1;

        // advance current tile + prefetch pointers (incremental, wrap-adjusted)
        t = tpre;
        bool wrap = (tpre == t1 - 1);
        tpre = wrap ? t0 : tpre + 1;
        kPre += wrap ? -(ptrdiff_t)(cnt - 1) * (64 * DK) : (ptrdiff_t)(64 * DK);
        vPre += wrap ? -(ptrdiff_t)(cnt - 1) * 64 : (ptrdiff_t)64;
    }

    // epilogue
    int b = bh >> 4, h = bh & 15;
    if (kk == 9) {
        // single chunk: normalize and write final bf16
        float lb[4];
#pragma unroll
        for (int i = 0; i < 4; i++) lb[i] = frcp(__shfl(lrow, r0 + i));
#pragma unroll
        for (int d = 0; d < 4; d++)
#pragma unroll
            for (int i = 0; i < 4; i++) {
                int qq = q0 + w * 16 + r0 + i;
                int dk = d * 16 + lr;
                size_t idx = ((size_t)(b * S_LEN + qq)) * D_DIM + h * DK + dk;
                Oa[idx] = bfc(o[d][i] * lb[i]);
            }
    } else {
        int jj = j - 24;               // split j's are 24..31
        if (kk == 0) {
            // chunk0 partial: unnormalized bf16 into the final O slot
#pragma unroll
            for (int d = 0; d < 4; d++)
#pragma unroll
                for (int i = 0; i < 4; i++) {
                    int qq = q0 + w * 16 + r0 + i;
                    int dk = d * 16 + lr;
                    size_t idx = ((size_t)(b * S_LEN + qq)) * D_DIM + h * DK + dk;
                    Oa[idx] = bfc(o[d][i]);
                }
        } else {
            // chunk1 partial: f32 into Pd scratch (d_out)
#pragma unroll
            for (int d = 0; d < 4; d++)
#pragma unroll
                for (int i = 0; i < 4; i++) {
                    int rloc = w * 16 + r0 + i;
                    Pd[((size_t)(bh * 8 + jj) * 64 + rloc) * 64 + d * 16 + lr] = o[d][i];
                }
        }
        if (lane < 16) {
            int row = w * 16 + lane;   // lanes 0..15 hold rows (q=lr) stats
            ml[(size_t)kk * 16384 + (bh * 8 + jj) * 64 + row] = make_float2(mrowL, lrow);
        }
    }
}

// ---------------- merge of split-tile partials (j = 24..31) ----------------
__global__ __launch_bounds__(256) void attn_merge(const float2* __restrict__ ml,
                                                  const float* __restrict__ Pd,
                                                  ushort_t* __restrict__ Oa) {
    int bh = blockIdx.x;           // 0..31
    int jj = blockIdx.y;           // 0..7 -> j = jj+24
    int tid = threadIdx.x;
    int r = tid >> 2;              // row 0..63
    int q = (tid & 3) * 16;        // dk start
    int b = bh >> 4, h = bh & 15;
    int row = (jj + 24) * 64 + r;
    float2 a = ml[(bh * 8 + jj) * 64 + r];
    float2 c = ml[16384 + (bh * 8 + jj) * 64 + r];
    float M = fmaxf(a.x, c.x);
    float w0 = fexp2(a.x - M), w1 = fexp2(c.x - M);
    float rc = frcp(a.y * w0 + c.y * w1);
    size_t ob = ((size_t)(b * S_LEN + row)) * D_DIM + h * DK + q;
    const float* p1 = &Pd[((size_t)(bh * 8 + jj) * 64 + r) * 64 + q];
#pragma unroll
    for (int i = 0; i < 4; i++) {
        ushort4 o0 = *(const ushort4*)&Oa[ob + i * 4];
        float4 o1 = *(const float4*)&p1[i * 4];
        ushort4 res;
        res.x = bfc((bf2f(o0.x) * w0 + o1.x * w1) * rc);
        res.y = bfc((bf2f(o0.y) * w0 + o1.y * w1) * rc);
        res.z = bfc((bf2f(o0.z) * w0 + o1.z * w1) * rc);
        res.w = bfc((bf2f(o0.w) * w0 + o1.w * w1) * rc);
        *(ushort4*)&Oa[ob + i * 4] = res;
    }
}

// ---------------- launch ----------------
extern "C" void kernel_launch(void* const* d_in, const int* in_sizes, int n_in,
                              void* d_out, int out_size, void* d_ws, size_t ws_size,
                              hipStream_t stream) {
    const float* X  = (const float*)d_in[0];
    const float* Wq = (const float*)d_in[1];
    const float* bq = (const float*)d_in[2];
    const float* Wk = (const float*)d_in[3];
    const float* bk = (const float*)d_in[4];
    const float* Wv = (const float*)d_in[5];
    const float* bv = (const float*)d_in[6];
    const float* Wo = (const float*)d_in[7];
    const float* bo = (const float*)d_in[8];
    float* out = (float*)d_out;

    char* ws = (char*)d_ws;
    ushort_t* Xb    = (ushort_t*)ws;                        // 8 MiB [M,D] bf16 (later: attn out)
    ushort_t* Wqkvb = (ushort_t*)(ws + (8u  << 20));        // 6 MiB; dead after QKV gemm
    float2*   mlbuf = (float2*)(ws + (8u  << 20));          // 256 KiB (over dead Wqkvb)
    ushort_t* Qb    = (ushort_t*)(ws + (14u << 20));        // 8 MiB [b,h,s,dk]
    ushort_t* Kb    = (ushort_t*)(ws + (22u << 20));        // 8 MiB [b,h,s,dk]
    ushort_t* Vtb   = (ushort_t*)(ws + (30u << 20));        // 8 MiB [b,h,dk,s]
    ushort_t* Wob   = Wqkvb;                                // reuse after merge
    ushort_t* Ab    = Xb;                                   // attn out reuses X slot
    float*    Pd    = out;                                  // chunk1 partials scratch (dead until Wo gemm)

    const int M = M_ROWS;
    int nX4 = (M * D_DIM) / 4;
    int nW4 = (D_DIM * D_DIM) / 4;

    cvt_bf16<<<2048, 256, 0, stream>>>(X, Xb, nX4);
    cvt_w3<<<2048, 256, 0, stream>>>(Wq, Wk, Wv, Wqkvb);

    // fused QKV: 32 x 24 = 768 blocks (3/CU)
    gemm_bt<3, 128, 128><<<dim3((M / 128) * (3072 / 128)), 256, 0, stream>>>(
        Xb, Wqkvb, bq, bk, bv, Qb, Kb, Vtb, M, 3072, D_DIM);

    // attn: 32 x 40 = 1280 chunk-blocks = exactly 5/CU, all co-resident
    dim3 agrid(BATCH * NH, 40);
    attn_fwd<<<agrid, 256, 0, stream>>>(Qb, Kb, Vtb, Ab, mlbuf, Pd);

    // merge split-tile partials (j=24..31)
    attn_merge<<<dim3(BATCH * NH, 8), 256, 0, stream>>>(mlbuf, Pd, Ab);

    cvt_bf16<<<2048, 256, 0, stream>>>(Wo, Wob, nW4);   // after merge (overlays mlbuf)

    // Wo gemm: 64x128 tiles -> 512 blocks (2/CU); overwrites all of d_out
    gemm_bt<2, 64, 128><<<dim3((M / 64) * (D_DIM / 128)), 256, 0, stream>>>(
        Ab, Wob, bo, bo, bo, out, out, out, M, D_DIM, D_DIM);
}

// Round 14
// 118.832 us; speedup vs baseline: 1.8149x; 1.0020x over previous
//
#include <hip/hip_runtime.h>
#include <hip/hip_bf16.h>
#include <cstdint>

typedef __attribute__((ext_vector_type(8))) short short8;
typedef __attribute__((ext_vector_type(4))) float f32x4;
typedef __attribute__((ext_vector_type(2))) unsigned int uint2v;
typedef unsigned short ushort_t;

#define S_LEN 2048
#define D_DIM 1024
#define NH 16
#define DK 64
#define BATCH 2
#define M_ROWS (BATCH * S_LEN)   // 4096
#define BK 32

__device__ inline ushort_t f2bf(float f) {
    union { float f; uint32_t u; } v; v.f = f;
    uint32_t r = v.u + 0x7fffu + ((v.u >> 16) & 1u);  // RNE
    return (ushort_t)(r >> 16);
}

__device__ __forceinline__ ushort_t bfc(float f) {
    __hip_bfloat16 h = __float2bfloat16(f);          // HW cvt path
    return __builtin_bit_cast(ushort_t, h);
}

__device__ __forceinline__ float bf2f(ushort_t u) {
    return __uint_as_float(((uint32_t)u) << 16);
}

// HW transcendentals (OCML exp2f/div are multi-instruction without fast-math)
__device__ __forceinline__ float fexp2(float x) {
#if __has_builtin(__builtin_amdgcn_exp2f)
    return __builtin_amdgcn_exp2f(x);
#else
    return exp2f(x);
#endif
}
__device__ __forceinline__ float frcp(float x) {
#if __has_builtin(__builtin_amdgcn_rcpf)
    return __builtin_amdgcn_rcpf(x);
#else
    return 1.0f / x;
#endif
}

__device__ __forceinline__ void glds16(const ushort_t* g, ushort_t* l) {
    __builtin_amdgcn_global_load_lds(
        (const __attribute__((address_space(1))) uint32_t*)g,
        (__attribute__((address_space(3))) uint32_t*)l,
        16, 0, 0);
}

#if __has_builtin(__builtin_amdgcn_permlane16_swap) && __has_builtin(__builtin_amdgcn_permlane32_swap)
#define HAS_PLSWAP 1
#else
#define HAS_PLSWAP 0
#endif

// cross-lane reduce over the 4 16-lane groups (lanes l, l^16, l^32, l^48)
__device__ __forceinline__ float red_max4(float x) {
#if HAS_PLSWAP
    uint2v a = __builtin_amdgcn_permlane16_swap(__float_as_uint(x), __float_as_uint(x), false, false);
    float y = fmaxf(__uint_as_float(a.x), __uint_as_float(a.y));
    uint2v b = __builtin_amdgcn_permlane32_swap(__float_as_uint(y), __float_as_uint(y), false, false);
    return fmaxf(__uint_as_float(b.x), __uint_as_float(b.y));
#else
    x = fmaxf(x, __shfl_xor(x, 16));
    return fmaxf(x, __shfl_xor(x, 32));
#endif
}
__device__ __forceinline__ float red_sum4(float x) {
#if HAS_PLSWAP
    uint2v a = __builtin_amdgcn_permlane16_swap(__float_as_uint(x), __float_as_uint(x), false, false);
    float y = __uint_as_float(a.x) + __uint_as_float(a.y);
    uint2v b = __builtin_amdgcn_permlane32_swap(__float_as_uint(y), __float_as_uint(y), false, false);
    return __uint_as_float(b.x) + __uint_as_float(b.y);
#else
    x += __shfl_xor(x, 16);
    return x + __shfl_xor(x, 32);
#endif
}

// T12 route: build PV A-frag words F[0..3] for k-slice ks from packed P words
// wp[n][h] (kv = 16n + 4*(lane>>4) + 2h + {0,1}, q = lane&15).
__device__ __forceinline__ void route_p(const uint32_t wp[4][2], int ks, int lane, uint32_t F[4]) {
#if HAS_PLSWAP
    uint32_t U0 = wp[2 * ks][0],     U1 = wp[2 * ks][1];
    uint32_t V0 = wp[2 * ks + 1][0], V1 = wp[2 * ks + 1][1];
    uint2v t, pa0, pa1, pb0, pb1;
    t = __builtin_amdgcn_permlane32_swap(U0, U0, false, false);
    pa0 = __builtin_amdgcn_permlane16_swap(U0, t.y, false, false);
    t = __builtin_amdgcn_permlane32_swap(U1, U1, false, false);
    pa1 = __builtin_amdgcn_permlane16_swap(U1, t.y, false, false);
    t = __builtin_amdgcn_permlane32_swap(V0, V0, false, false);
    pb0 = __builtin_amdgcn_permlane16_swap(t.x, V0, false, false);
    t = __builtin_amdgcn_permlane32_swap(V1, V1, false, false);
    pb1 = __builtin_amdgcn_permlane16_swap(t.x, V1, false, false);
    bool lo = lane < 32;
    F[0] = lo ? pa0.x : pb0.x;
    F[1] = lo ? pa1.x : pb1.x;
    F[2] = lo ? pa0.y : pb0.y;
    F[3] = lo ? pa1.y : pb1.y;
#else
    int q = lane & 15, g = lane >> 4;
#pragma unroll
    for (int m = 0; m < 4; m++) {
        int src = 16 * (2 * (g & 1) + (m >> 1)) + q;
        uint32_t xa = (uint32_t)__shfl((int)wp[2 * ks][m & 1], src);
        uint32_t xb = (uint32_t)__shfl((int)wp[2 * ks + 1][m & 1], src);
        F[m] = (g < 2) ? xa : xb;
    }
#endif
}

// ---------------- fp32 -> bf16 convert (vectorized) ----------------
__global__ void cvt_bf16(const float* __restrict__ in, ushort_t* __restrict__ out, int n4) {
    int i = blockIdx.x * blockDim.x + threadIdx.x;
    int stride = gridDim.x * blockDim.x;
    for (int idx = i; idx < n4; idx += stride) {
        float4 v = ((const float4*)in)[idx];
        ushort4 o;
        o.x = f2bf(v.x); o.y = f2bf(v.y); o.z = f2bf(v.z); o.w = f2bf(v.w);
        ((ushort4*)out)[idx] = o;
    }
}

// fused convert of Wq,Wk,Wv into one [3072,1024] bf16 buffer
__global__ void cvt_w3(const float* __restrict__ wq, const float* __restrict__ wk,
                       const float* __restrict__ wv, ushort_t* __restrict__ wqkv) {
    const int seg = (D_DIM * D_DIM) / 4;   // 2^18
    int i = blockIdx.x * blockDim.x + threadIdx.x;
    int stride = gridDim.x * blockDim.x;
    for (int idx = i; idx < 3 * seg; idx += stride) {
        int sel = idx >> 18;
        int id = idx & (seg - 1);
        const float* src = sel == 0 ? wq : (sel == 1 ? wk : wv);
        float4 v = ((const float4*)src)[id];
        ushort4 o;
        o.x = f2bf(v.x); o.y = f2bf(v.y); o.z = f2bf(v.z); o.w = f2bf(v.w);
        ((ushort4*)wqkv)[sel * seg + id] = o;
    }
}

// ---------------- GEMM: C = A[M,K] * Bw[N,K]^T + bias ----------------
// T1 XCD remap + single-barrier double-buffered staging.
template<int MODE, int BMt, int BNt>
__global__ __launch_bounds__(256, 3) void gemm_bt(const ushort_t* __restrict__ A,
                                                  const ushort_t* __restrict__ Bw,
                                                  const float* __restrict__ b0,
                                                  const float* __restrict__ b1,
                                                  const float* __restrict__ b2,
                                                  void* __restrict__ C0,
                                                  void* __restrict__ C1,
                                                  void* __restrict__ C2,
                                                  int M, int N, int K) {
    constexpr int FM = BMt / 32, FN = BNt / 32;
    constexpr int ACH = BMt / 64, BCH = BNt / 64;
    __shared__ ushort_t As[2][BMt * BK];
    __shared__ ushort_t Bs[2][BNt * BK];
    int tid = threadIdx.x;
    int lane = tid & 63;
    int w = tid >> 6;
    int wr = w >> 1, wc = w & 1;
    // XCD-aware remap: consecutive logical tiles (same A panel) -> same XCD L2
    int nwg = gridDim.x;
    int bx = (blockIdx.x & 7) * (nwg >> 3) + (blockIdx.x >> 3);
    int ntile = N / BNt;
    int m0 = (bx / ntile) * BMt;
    int n0 = (bx % ntile) * BNt;
    int lr = lane & 15;
    int lk = (lane >> 4) * 8;
    int srow = lane >> 2;            // 0..15
    int scol = (lane & 3) * 8;

    auto stage = [&](int b, int kt) {
#pragma unroll
        for (int c = 0; c < ACH; c++)
            glds16(&A[(size_t)(m0 + w * (BMt / 4) + c * 16 + srow) * K + kt + scol],
                   &As[b][(w * (BMt / 4) + c * 16) * BK]);
#pragma unroll
        for (int c = 0; c < BCH; c++)
            glds16(&Bw[(size_t)(n0 + w * (BNt / 4) + c * 16 + srow) * K + kt + scol],
                   &Bs[b][(w * (BNt / 4) + c * 16) * BK]);
    };

    f32x4 acc[FM][FN] = {};

    stage(0, 0);
    __syncthreads();                 // drain prologue glds
    int cur = 0;
    for (int kt = 0; kt < K; kt += BK) {
        if (kt + BK < K) stage(cur ^ 1, kt + BK);   // next tile in flight

        short8 af[FM], bf[FN];
#pragma unroll
        for (int f = 0; f < FM; f++)
            af[f] = *(const short8*)&As[cur][(wr * (BMt / 2) + f * 16 + lr) * BK + lk];
#pragma unroll
        for (int f = 0; f < FN; f++)
            bf[f] = *(const short8*)&Bs[cur][(wc * (BNt / 2) + f * 16 + lr) * BK + lk];
#pragma unroll
        for (int i = 0; i < FM; i++)
#pragma unroll
            for (int j = 0; j < FN; j++)
                acc[i][j] = __builtin_amdgcn_mfma_f32_16x16x32_bf16(af[i], bf[j], acc[i][j], 0, 0, 0);

        __syncthreads();             // drains this iter's glds + ds_reads
        cur ^= 1;
    }

    int r0 = (lane >> 4) * 4;
#pragma unroll
    for (int j = 0; j < FN; j++) {
        int ncol = n0 + wc * (BNt / 2) + j * 16 + lr;
        if (MODE == 2) {
            float bv = b0[ncol];
#pragma unroll
            for (int i = 0; i < FM; i++) {
                int mbase = m0 + wr * (BMt / 2) + i * 16 + r0;
#pragma unroll
                for (int r = 0; r < 4; r++)
                    ((float*)C0)[(size_t)(mbase + r) * N + ncol] = acc[i][j][r] + bv;
            }
        } else {
            int sel = n0 >> 10;                    // block-uniform
            const float* bp = sel == 0 ? b0 : (sel == 1 ? b1 : b2);
            int nc = ncol & 1023;
            float bv = bp[nc];
            int hh = nc >> 6, dk = nc & 63;
            ushort_t* Co = (ushort_t*)(sel == 0 ? C0 : (sel == 1 ? C1 : C2));
#pragma unroll
            for (int i = 0; i < FM; i++) {
                int mbase = m0 + wr * (BMt / 2) + i * 16 + r0;
                int bb = mbase >> 11, ss = mbase & 2047;
                if (sel == 2) {
                    ushort4 pk;
                    pk.x = f2bf(acc[i][j][0] + bv);
                    pk.y = f2bf(acc[i][j][1] + bv);
                    pk.z = f2bf(acc[i][j][2] + bv);
                    pk.w = f2bf(acc[i][j][3] + bv);
                    size_t idx = ((size_t)(bb * NH + hh) * DK + dk) * S_LEN + ss;
                    *(ushort4*)&Co[idx] = pk;
                } else {
#pragma unroll
                    for (int r = 0; r < 4; r++) {
                        size_t idx = ((size_t)(bb * NH + hh) * S_LEN + (ss + r)) * DK + dk;
                        Co[idx] = f2bf(acc[i][j][r] + bv);
                    }
                }
            }
        }
    }
}

// ---------------- Flash attention (causal, kv-split, full-residency) ----------------
// Round-13 structure. NEW: LDS addresses hoisted out of the loop. The swizzle
// algebra collapses because row = n*16+lr has (row&7) = (lr&7): all 16 K/V
// reads reduce to two lane-constant bases (swLo/swHi) + compile-time n*1024 /
// d*1024 element offsets (-> ds_read_b128 with immediate offset); staging
// writes reduce to one base wOff (+2048 for the +32-row partner).
#define CSC 0.1803368801f   // 0.125 * log2(e)

__device__ const unsigned char JTAB[40] = {
    23,22,21,20,19,18,17,16,
    31,31,30,28,29,26,27,15,
    24,25,30,28,29,27,26,14,
    24,11, 9,10, 8,25,12,13,
     0, 1, 2, 4, 6, 5, 7, 3};
__device__ const unsigned char KTAB[40] = {
     9, 9, 9, 9, 9, 9, 9, 9,
     0, 1, 0, 0, 0, 0, 1, 9,
     0, 0, 1, 1, 1, 0, 1, 9,
     1, 9, 9, 9, 9, 1, 9, 9,
     9, 9, 9, 9, 9, 9, 9, 9};

__global__ __launch_bounds__(256, 5) void attn_fwd(const ushort_t* __restrict__ Q,
                                                   const ushort_t* __restrict__ K,
                                                   const ushort_t* __restrict__ Vt,
                                                   ushort_t* __restrict__ Oa,
                                                   float2* __restrict__ ml,
                                                   float* __restrict__ Pd) {
    __shared__ ushort_t Ks[2][64 * 64];
    __shared__ ushort_t Vs[2][64 * 64];

    int tid = threadIdx.x;
    int lane = tid & 63;
    int w = tid >> 6;
    int bh = blockIdx.x;           // 0..31
    int yy = blockIdx.y;           // 0..39
    int j = JTAB[yy];
    int kk = KTAB[yy];             // 0/1 = split chunk, 9 = single
    int nt = j + 1;
    int half = (nt + 1) >> 1;
    int t0 = (kk == 1) ? half : 0;
    int t1 = (kk == 0) ? half : nt;
    int cnt = t1 - t0;
    int off = yy % cnt;            // per-block stagger (same-CU mates differ)
    size_t base = (size_t)bh * S_LEN * DK;
    int q0 = j * 64;

    int lr = lane & 15;
    int lk = (lane >> 4) * 8;
    int g16 = (lane >> 4) * 16;    // byte col of fragment k-slice
    int r0 = (lane >> 4) * 4;
    int wq = w * 16 + lr;          // this lane's q row (within tile)

    // Hoisted LDS read bases (elements). For row = n*16+lr: (row&7)==(lr&7),
    // so swz(n*16+lr, cb) = n*1024 + ((lr*128 + (cb ^ ((lr&7)<<4))) >> 1).
    int swb = (lr & 7) << 4;
    int swLo = (lr * 128 + (g16 ^ swb)) >> 1;          // cb = g16        (slice 0 / ks 0)
    int swHi = (lr * 128 + ((64 + g16) ^ swb)) >> 1;   // cb = 64 + g16   (slice 1 / ks 1)

    // Q fragment (16 rows per wave)
    short8 qf0 = *(const short8*)&Q[base + (size_t)(q0 + wq) * DK + lk];
    short8 qf1 = *(const short8*)&Q[base + (size_t)(q0 + wq) * DK + 32 + lk];

    f32x4 o[4] = {};
    float mrowL = -1e30f, lrow = 0.f;

    int sr = tid >> 3;            // 0..31
    int scb = (tid & 7) * 16;     // byte col
    // Hoisted staging write base; row sr+32 has same (&7) -> +32*64 elements.
    int wOff = (sr * 128 + (scb ^ ((sr & 7) << 4))) >> 1;

    // staging source bases (strength-reduced; advance incrementally)
    const ushort_t* kBase = K  + base + (size_t)sr * DK + ((tid & 7) * 8);
    const ushort_t* vBase = Vt + base + (size_t)sr * S_LEN + ((tid & 7) * 8);

    // prologue: stage first (staggered) tile into buf 0 (swizzled)
    int tf = t0 + off;
    {
        const ushort_t* kp = kBase + (size_t)tf * (64 * DK);
        const ushort_t* vp = vBase + (size_t)tf * 64;
        *(uint4*)&Ks[0][wOff]        = *(const uint4*)kp;
        *(uint4*)&Ks[0][wOff + 2048] = *(const uint4*)(kp + 32 * DK);
        *(uint4*)&Vs[0][wOff]        = *(const uint4*)vp;
        *(uint4*)&Vs[0][wOff + 2048] = *(const uint4*)(vp + 32 * S_LEN);
    }
    __syncthreads();

    int t = tf;                                    // current tile
    int tpre = (tf == t1 - 1) ? t0 : tf + 1;       // prefetch target
    const ushort_t* kPre = kBase + (size_t)tpre * (64 * DK);
    const ushort_t* vPre = vBase + (size_t)tpre * 64;

    int cur = 0;
    for (int s = 0; s < cnt; ++s) {
        bool last = (s == cnt - 1);
        bool diag = (t == j);
        uint4 kr0, kr1, vr0, vr1;
        if (!last) {
            kr0 = *(const uint4*)kPre;
            kr1 = *(const uint4*)(kPre + 32 * DK);
            vr0 = *(const uint4*)vPre;
            vr1 = *(const uint4*)(vPre + 32 * S_LEN);
        }

        // swapped QK^T: st rows = kv (regs), cols = q (lanes)
        f32x4 st[4] = {};
        __builtin_amdgcn_s_setprio(1);
#pragma unroll
        for (int n = 0; n < 4; n++) {
            if (!diag || n <= w) {   // skip fully-masked kv frags on diagonal
                short8 kf0 = *(const short8*)&Ks[cur][swLo + n * 1024];
                short8 kf1 = *(const short8*)&Ks[cur][swHi + n * 1024];
                st[n] = __builtin_amdgcn_mfma_f32_16x16x32_bf16(kf0, qf0, st[n], 0, 0, 0);
                st[n] = __builtin_amdgcn_mfma_f32_16x16x32_bf16(kf1, qf1, st[n], 0, 0, 0);
            }
        }
        __builtin_amdgcn_s_setprio(0);

        if (diag) {   // causal mask within diagonal tile
#pragma unroll
            for (int n = 0; n < 4; n++)
#pragma unroll
                for (int i = 0; i < 4; i++)
                    if (16 * n + r0 + i > wq) st[n][i] = -1e30f;
        }

        // per-lane softmax (q = lr), reduce across 4 lane-groups
        float m0 = fmaxf(fmaxf(fmaxf(st[0][0], st[0][1]), st[0][2]), st[0][3]);
        float m1 = fmaxf(fmaxf(fmaxf(st[1][0], st[1][1]), st[1][2]), st[1][3]);
        float m2 = fmaxf(fmaxf(fmaxf(st[2][0], st[2][1]), st[2][2]), st[2][3]);
        float m3 = fmaxf(fmaxf(fmaxf(st[3][0], st[3][1]), st[3][2]), st[3][3]);
        float mx = fmaxf(fmaxf(fmaxf(m0, m1), m2), m3);
        float mxL = red_max4(mx) * CSC;

        bool skip = __all(mxL <= mrowL + 8.0f);   // T13 defer-max
        float corr = 1.0f;
        float mnewL = mrowL;
        if (!skip) {
            mnewL = fmaxf(mrowL, mxL);
            corr = fexp2(mrowL - mnewL);
            mrowL = mnewL;
        }

        float psum = 0.f;
        uint32_t wp[4][2];
#pragma unroll
        for (int n = 0; n < 4; n++) {
#pragma unroll
            for (int i = 0; i < 4; i++) {
                float p = fexp2(fmaf(st[n][i], CSC, -mnewL));
                st[n][i] = p;
                psum += p;
            }
            wp[n][0] = (uint32_t)bfc(st[n][0]) | ((uint32_t)bfc(st[n][1]) << 16);
            wp[n][1] = (uint32_t)bfc(st[n][2]) | ((uint32_t)bfc(st[n][3]) << 16);
        }
        psum = red_sum4(psum);

        if (skip) {
            lrow += psum;
        } else {
            lrow = lrow * corr + psum;
            float cb[4];
#pragma unroll
            for (int i = 0; i < 4; i++) cb[i] = __shfl(corr, r0 + i);
#pragma unroll
            for (int d = 0; d < 4; d++)
#pragma unroll
                for (int i = 0; i < 4; i++) o[d][i] *= cb[i];
        }

        // PV: O += P V, P frags routed in-register
#pragma unroll
        for (int ks = 0; ks < 2; ks++) {
            if (diag && 32 * ks > w * 16 + 15) continue;  // slice fully masked
            uint32_t F[4];
            route_p(wp, ks, lane, F);
            union { uint32_t u[4]; short8 s; } pu;
            pu.u[0] = F[0]; pu.u[1] = F[1]; pu.u[2] = F[2]; pu.u[3] = F[3];
            short8 pf = pu.s;
            int vb = (ks ? swHi : swLo);              // compile-time select
            __builtin_amdgcn_s_setprio(1);
#pragma unroll
            for (int d = 0; d < 4; d++) {
                short8 vf = *(const short8*)&Vs[cur][vb + d * 1024];
                o[d] = __builtin_amdgcn_mfma_f32_16x16x32_bf16(pf, vf, o[d], 0, 0, 0);
            }
            __builtin_amdgcn_s_setprio(0);
        }

        if (!last) {
            *(uint4*)&Ks[cur ^ 1][wOff]        = kr0;
            *(uint4*)&Ks[cur ^ 1][wOff + 2048] = kr1;
            *(uint4*)&Vs[cur ^ 1][wOff]        = vr0;
            *(uint4*)&Vs[cur ^ 1][wOff + 2048] = vr1;
        }
        __syncthreads();
        cur ^= 1;

        // advance current tile + prefetch pointers (incremental, wrap-adjusted)
        t = tpre;
        bool wrap = (tpre == t1 - 1);
        tpre = wrap ? t0 : tpre + 1;
        kPre += wrap ? -(ptrdiff_t)(cnt - 1) * (64 * DK) : (ptrdiff_t)(64 * DK);
        vPre += wrap ? -(ptrdiff_t)(cnt - 1) * 64 : (ptrdiff_t)64;
    }

    // epilogue
    int b = bh >> 4, h = bh & 15;
    if (kk == 9) {
        // single chunk: normalize and write final bf16
        float lb[4];
#pragma unroll
        for (int i = 0; i < 4; i++) lb[i] = frcp(__shfl(lrow, r0 + i));
#pragma unroll
        for (int d = 0; d < 4; d++)
#pragma unroll
            for (int i = 0; i < 4; i++) {
                int qq = q0 + w * 16 + r0 + i;
                int dk = d * 16 + lr;
                size_t idx = ((size_t)(b * S_LEN + qq)) * D_DIM + h * DK + dk;
                Oa[idx] = bfc(o[d][i] * lb[i]);
            }
    } else {
        int jj = j - 24;               // split j's are 24..31
        if (kk == 0) {
            // chunk0 partial: unnormalized bf16 into the final O slot
#pragma unroll
            for (int d = 0; d < 4; d++)
#pragma unroll
                for (int i = 0; i < 4; i++) {
                    int qq = q0 + w * 16 + r0 + i;
                    int dk = d * 16 + lr;
                    size_t idx = ((size_t)(b * S_LEN + qq)) * D_DIM + h * DK + dk;
                    Oa[idx] = bfc(o[d][i]);
                }
        } else {
            // chunk1 partial: f32 into Pd scratch (d_out)
#pragma unroll
            for (int d = 0; d < 4; d++)
#pragma unroll
                for (int i = 0; i < 4; i++) {
                    int rloc = w * 16 + r0 + i;
                    Pd[((size_t)(bh * 8 + jj) * 64 + rloc) * 64 + d * 16 + lr] = o[d][i];
                }
        }
        if (lane < 16) {
            int row = w * 16 + lane;   // lanes 0..15 hold rows (q=lr) stats
            ml[(size_t)kk * 16384 + (bh * 8 + jj) * 64 + row] = make_float2(mrowL, lrow);
        }
    }
}

// ---------------- merge of split-tile partials (j = 24..31) ----------------
__global__ __launch_bounds__(256) void attn_merge(const float2* __restrict__ ml,
                                                  const float* __restrict__ Pd,
                                                  ushort_t* __restrict__ Oa) {
    int bh = blockIdx.x;           // 0..31
    int jj = blockIdx.y;           // 0..7 -> j = jj+24
    int tid = threadIdx.x;
    int r = tid >> 2;              // row 0..63
    int q = (tid & 3) * 16;        // dk start
    int b = bh >> 4, h = bh & 15;
    int row = (jj + 24) * 64 + r;
    float2 a = ml[(bh * 8 + jj) * 64 + r];
    float2 c = ml[16384 + (bh * 8 + jj) * 64 + r];
    float M = fmaxf(a.x, c.x);
    float w0 = fexp2(a.x - M), w1 = fexp2(c.x - M);
    float rc = frcp(a.y * w0 + c.y * w1);
    size_t ob = ((size_t)(b * S_LEN + row)) * D_DIM + h * DK + q;
    const float* p1 = &Pd[((size_t)(bh * 8 + jj) * 64 + r) * 64 + q];
#pragma unroll
    for (int i = 0; i < 4; i++) {
        ushort4 o0 = *(const ushort4*)&Oa[ob + i * 4];
        float4 o1 = *(const float4*)&p1[i * 4];
        ushort4 res;
        res.x = bfc((bf2f(o0.x) * w0 + o1.x * w1) * rc);
        res.y = bfc((bf2f(o0.y) * w0 + o1.y * w1) * rc);
        res.z = bfc((bf2f(o0.z) * w0 + o1.z * w1) * rc);
        res.w = bfc((bf2f(o0.w) * w0 + o1.w * w1) * rc);
        *(ushort4*)&Oa[ob + i * 4] = res;
    }
}

// ---------------- launch ----------------
extern "C" void kernel_launch(void* const* d_in, const int* in_sizes, int n_in,
                              void* d_out, int out_size, void* d_ws, size_t ws_size,
                              hipStream_t stream) {
    const float* X  = (const float*)d_in[0];
    const float* Wq = (const float*)d_in[1];
    const float* bq = (const float*)d_in[2];
    const float* Wk = (const float*)d_in[3];
    const float* bk = (const float*)d_in[4];
    const float* Wv = (const float*)d_in[5];
    const float* bv = (const float*)d_in[6];
    const float* Wo = (const float*)d_in[7];
    const float* bo = (const float*)d_in[8];
    float* out = (float*)d_out;

    char* ws = (char*)d_ws;
    ushort_t* Xb    = (ushort_t*)ws;                        // 8 MiB [M,D] bf16 (later: attn out)
    ushort_t* Wqkvb = (ushort_t*)(ws + (8u  << 20));        // 6 MiB; dead after QKV gemm
    float2*   mlbuf = (float2*)(ws + (8u  << 20));          // 256 KiB (over dead Wqkvb)
    ushort_t* Qb    = (ushort_t*)(ws + (14u << 20));        // 8 MiB [b,h,s,dk]
    ushort_t* Kb    = (ushort_t*)(ws + (22u << 20));        // 8 MiB [b,h,s,dk]
    ushort_t* Vtb   = (ushort_t*)(ws + (30u << 20));        // 8 MiB [b,h,dk,s]
    ushort_t* Wob   = Wqkvb;                                // reuse after merge
    ushort_t* Ab    = Xb;                                   // attn out reuses X slot
    float*    Pd    = out;                                  // chunk1 partials scratch (dead until Wo gemm)

    const int M = M_ROWS;
    int nX4 = (M * D_DIM) / 4;
    int nW4 = (D_DIM * D_DIM) / 4;

    cvt_bf16<<<2048, 256, 0, stream>>>(X, Xb, nX4);
    cvt_w3<<<2048, 256, 0, stream>>>(Wq, Wk, Wv, Wqkvb);

    // fused QKV: 32 x 24 = 768 blocks (3/CU)
    gemm_bt<3, 128, 128><<<dim3((M / 128) * (3072 / 128)), 256, 0, stream>>>(
        Xb, Wqkvb, bq, bk, bv, Qb, Kb, Vtb, M, 3072, D_DIM);

    // attn: 32 x 40 = 1280 chunk-blocks = exactly 5/CU, all co-resident
    dim3 agrid(BATCH * NH, 40);
    attn_fwd<<<agrid, 256, 0, stream>>>(Qb, Kb, Vtb, Ab, mlbuf, Pd);

    // merge split-tile partials (j=24..31)
    attn_merge<<<dim3(BATCH * NH, 8), 256, 0, stream>>>(mlbuf, Pd, Ab);

    cvt_bf16<<<2048, 256, 0, stream>>>(Wo, Wob, nW4);   // after merge (overlays mlbuf)

    // Wo gemm: 64x128 tiles -> 512 blocks (2/CU); overwrites all of d_out
    gemm_bt<2, 64, 128><<<dim3((M / 64) * (D_DIM / 128)), 256, 0, stream>>>(
        Ab, Wob, bo, bo, bo, out, out, out, M, D_DIM, D_DIM);
}